// Round 1
// baseline (1627.596 us; speedup 1.0000x reference)
//
#include <hip/hip_runtime.h>
#include <math.h>

// ---------------------------------------------------------------------------
// Mamba block forward, f32.  b=4, l=1024, dm=1024, di=2048, n=16, r=64.
// All activations kept in (b*l, feature) row-major layout so every einsum is
// a plain NT GEMM:  C[m, e] = sum_k A[m, k] * W[e, k].
// ---------------------------------------------------------------------------

#define BM 64
#define BN 64
#define BK 16

// Generic NT GEMM: A (M x K, lda), W (N x K, ldw), C (M x N, ldc).
// epi: 0 = none, 1 = softplus.
// M must be a multiple of 64, K a multiple of 16. N is guarded.
__global__ __launch_bounds__(256) void gemm_nt(
    const float* __restrict__ A, const float* __restrict__ W,
    float* __restrict__ C, int M, int N, int K,
    int lda, int ldw, int ldc, int epi)
{
  __shared__ float As[BK][BM + 1];
  __shared__ float Ws[BK][BN + 1];
  const int tid = threadIdx.y * 16 + threadIdx.x;
  const int row0 = blockIdx.y * BM;
  const int col0 = blockIdx.x * BN;
  float c[4][4] = {};
  for (int k0 = 0; k0 < K; k0 += BK) {
#pragma unroll
    for (int i = 0; i < 4; i++) {
      int e = tid + i * 256;
      int m = e >> 4, kk = e & 15;
      As[kk][m] = A[(size_t)(row0 + m) * lda + k0 + kk];
    }
#pragma unroll
    for (int i = 0; i < 4; i++) {
      int e = tid + i * 256;
      int n = e >> 4, kk = e & 15;
      float v = 0.f;
      if (col0 + n < N) v = W[(size_t)(col0 + n) * ldw + k0 + kk];
      Ws[kk][n] = v;
    }
    __syncthreads();
#pragma unroll
    for (int kk = 0; kk < BK; kk++) {
      float a[4], b[4];
#pragma unroll
      for (int i = 0; i < 4; i++) a[i] = As[kk][threadIdx.y + 16 * i];
#pragma unroll
      for (int j = 0; j < 4; j++) b[j] = Ws[kk][threadIdx.x + 16 * j];
#pragma unroll
      for (int i = 0; i < 4; i++)
#pragma unroll
        for (int j = 0; j < 4; j++)
          c[i][j] = fmaf(a[i], b[j], c[i][j]);
    }
    __syncthreads();
  }
#pragma unroll
  for (int i = 0; i < 4; i++) {
    int r = row0 + threadIdx.y + 16 * i;
#pragma unroll
    for (int j = 0; j < 4; j++) {
      int cc = col0 + threadIdx.x + 16 * j;
      if (cc < N) {
        float v = c[i][j];
        if (epi == 1) v = (v > 20.f) ? v : log1pf(expf(v));
        C[(size_t)r * ldc + cc] = v;
      }
    }
  }
}

// Depthwise causal conv (K=4) + bias + silu.
// xz: (4096 x 4096), x_pre = cols [0,2048). Output x: (4096 x 2048).
__global__ __launch_bounds__(256) void conv_silu_k(
    const float* __restrict__ xz, const float* __restrict__ conv_w,
    const float* __restrict__ conv_b, float* __restrict__ x)
{
  const int d = blockIdx.x * 256 + threadIdx.x;   // 0..2047
  const int row = blockIdx.y;                     // b*1024 + l
  const int l = row & 1023;
  const float4 w = ((const float4*)conv_w)[d];
  float acc = conv_b[d];
  const float* base = xz + (size_t)row * 4096 + d;
  if (l >= 3) acc = fmaf(base[-3 * 4096], w.x, acc);
  if (l >= 2) acc = fmaf(base[-2 * 4096], w.y, acc);
  if (l >= 1) acc = fmaf(base[-1 * 4096], w.z, acc);
  acc = fmaf(base[0], w.w, acc);
  x[(size_t)row * 2048 + d] = acc / (1.f + expf(-acc));
}

// Selective scan. Each thread: one d channel x 4 of the 16 states.
// block = 128 threads = 32 d-channels, grid = (2048/32, 4 batches).
// Chunks of 16 timesteps staged in LDS. Output written IN-PLACE over delta.
#define SDB 32   // d-channels per block
#define LCH 16   // timesteps per chunk

__global__ __launch_bounds__(128) void scan_k(
    const float* __restrict__ delta,
    const float* __restrict__ x,
    const float* __restrict__ xz,     // z at cols [2048,4096)
    const float* __restrict__ x_dbl,  // (4096 x 96): dt|B|C
    const float* __restrict__ A_log,
    const float* __restrict__ Dvec,
    float* __restrict__ out)          // == delta (in-place)
{
  __shared__ __align__(16) float sdelta[LCH][SDB];
  __shared__ __align__(16) float sx[LCH][SDB];
  __shared__ __align__(16) float sz[LCH][SDB];
  __shared__ __align__(16) float sB[LCH][16];
  __shared__ __align__(16) float sC[LCH][16];
  __shared__ __align__(16) float sOut[LCH][SDB];

  const int tid = threadIdx.x;     // 0..127
  const int dl = tid >> 2;         // 0..31
  const int ng = tid & 3;          // 0..3 (4 states each)
  const int d0 = blockIdx.x * SDB;
  const int b = blockIdx.y;
  const int d = d0 + dl;
  const size_t brow = (size_t)b * 1024;

  float Areg[4];
#pragma unroll
  for (int i = 0; i < 4; i++) Areg[i] = -expf(A_log[d * 16 + ng * 4 + i]);
  const float Dd = Dvec[d];
  float h[4] = {0.f, 0.f, 0.f, 0.f};

  for (int c0 = 0; c0 < 1024; c0 += LCH) {
#pragma unroll
    for (int i = 0; i < 4; i++) {
      int e = tid + i * 128;            // 0..511
      int lr = e >> 5, dd = e & 31;
      size_t row = brow + c0 + lr;
      sdelta[lr][dd] = delta[row * 2048 + d0 + dd];
      sx[lr][dd] = x[row * 2048 + d0 + dd];
      sz[lr][dd] = xz[row * 4096 + 2048 + d0 + dd];
    }
#pragma unroll
    for (int i = 0; i < 2; i++) {
      int e = tid + i * 128;            // 0..255
      int lr = e >> 4, nn = e & 15;
      size_t row = brow + c0 + lr;
      sB[lr][nn] = x_dbl[row * 96 + 64 + nn];
      sC[lr][nn] = x_dbl[row * 96 + 80 + nn];
    }
    __syncthreads();
#pragma unroll
    for (int s = 0; s < LCH; s++) {
      float dlt = sdelta[s][dl];
      float xv = sx[s][dl];
      float dx = dlt * xv;
      const float4 Bv = *(const float4*)&sB[s][ng * 4];
      const float4 Cv = *(const float4*)&sC[s][ng * 4];
      float acc;
      h[0] = expf(dlt * Areg[0]) * h[0] + dx * Bv.x; acc  = h[0] * Cv.x;
      h[1] = expf(dlt * Areg[1]) * h[1] + dx * Bv.y; acc += h[1] * Cv.y;
      h[2] = expf(dlt * Areg[2]) * h[2] + dx * Bv.z; acc += h[2] * Cv.z;
      h[3] = expf(dlt * Areg[3]) * h[3] + dx * Bv.w; acc += h[3] * Cv.w;
      acc += __shfl_xor(acc, 1);
      acc += __shfl_xor(acc, 2);
      if (ng == 0) {
        float zv = sz[s][dl];
        float silu_z = zv / (1.f + expf(-zv));
        sOut[s][dl] = (acc + xv * Dd) * silu_z;
      }
    }
    __syncthreads();
#pragma unroll
    for (int i = 0; i < 4; i++) {
      int e = tid + i * 128;
      int lr = e >> 5, dd = e & 31;
      size_t row = brow + c0 + lr;
      out[row * 2048 + d0 + dd] = sOut[lr][dd];
    }
  }
}

extern "C" void kernel_launch(void* const* d_in, const int* in_sizes, int n_in,
                              void* d_out, int out_size, void* d_ws, size_t ws_size,
                              hipStream_t stream)
{
  const float* hidden     = (const float*)d_in[0];  // (4,1024,1024)
  const float* in_proj_w  = (const float*)d_in[1];  // (4096,1024)
  const float* conv_w     = (const float*)d_in[2];  // (2048,4)
  const float* conv_b     = (const float*)d_in[3];  // (2048,)
  const float* x_proj_w   = (const float*)d_in[4];  // (96,2048)
  const float* dt_proj_w  = (const float*)d_in[5];  // (2048,64)
  const float* A_log      = (const float*)d_in[6];  // (2048,16)
  const float* Dvec       = (const float*)d_in[7];  // (2048,)
  const float* out_proj_w = (const float*)d_in[8];  // (1024,2048)
  float* out = (float*)d_out;                       // (4,1024,1024)

  float* xz    = (float*)d_ws;           // 4096 x 4096  (x_pre | z)
  float* x     = xz + (size_t)4096 * 4096;     // 4096 x 2048
  float* x_dbl = x + (size_t)4096 * 2048;      // 4096 x 96
  float* delta = x_dbl + (size_t)4096 * 96;    // 4096 x 2048 (also out buf)

  dim3 blk(16, 16);
  // xz = hidden @ in_proj_w^T   (M=4096, N=4096, K=1024)
  gemm_nt<<<dim3(64, 64), blk, 0, stream>>>(hidden, in_proj_w, xz,
                                            4096, 4096, 1024, 1024, 1024, 4096, 0);
  // x = silu(depthwise_conv(x_pre) + conv_b)
  conv_silu_k<<<dim3(8, 4096), 256, 0, stream>>>(xz, conv_w, conv_b, x);
  // x_dbl = x @ x_proj_w^T      (M=4096, N=96, K=2048)
  gemm_nt<<<dim3(2, 64), blk, 0, stream>>>(x, x_proj_w, x_dbl,
                                           4096, 96, 2048, 2048, 2048, 96, 0);
  // delta = softplus(dt @ dt_proj_w^T)  (M=4096, N=2048, K=64; dt = x_dbl[:, :64])
  gemm_nt<<<dim3(32, 64), blk, 0, stream>>>(x_dbl, dt_proj_w, delta,
                                            4096, 2048, 64, 96, 64, 2048, 1);
  // selective scan + epilogue, in-place over delta
  scan_k<<<dim3(64, 4), 128, 0, stream>>>(delta, x, xz, x_dbl, A_log, Dvec, delta);
  // out = scan_out @ out_proj_w^T  (M=4096, N=1024, K=2048)
  gemm_nt<<<dim3(16, 64), blk, 0, stream>>>(delta, out_proj_w, out,
                                            4096, 1024, 2048, 2048, 2048, 1024, 0);
}

// Round 2
// 746.794 us; speedup vs baseline: 2.1794x; 2.1794x over previous
//
#include <hip/hip_runtime.h>
#include <math.h>

// ---------------------------------------------------------------------------
// Mamba block forward. b=4, l=1024, dm=1024, di=2048, n=16, r=64.
// GEMMs now run on MFMA via bf16 hi/lo split (3 MFMA per product):
//   A*B ~= Ahi*Bhi + Ahi*Blo + Alo*Bhi   (rel err ~2^-17, f32 accumulate)
// ---------------------------------------------------------------------------

typedef __bf16 bf16x8 __attribute__((ext_vector_type(8)));
typedef float f32x4 __attribute__((ext_vector_type(4)));

#define TM 128
#define TN 128
#define TK 32

__device__ __forceinline__ void cvt_hilo(const float* f, bf16x8& h, bf16x8& l) {
#pragma unroll
  for (int i = 0; i < 8; i++) {
    float v = f[i];
    __bf16 hh = (__bf16)v;
    h[i] = hh;
    l[i] = (__bf16)(v - (float)hh);
  }
}

// NT GEMM on MFMA: A (M x K, lda) f32, W (N x K, ldw) f32, C (M x N, ldc) f32.
// epi: 0 = none, 1 = softplus. M % 128 == 0, K % 32 == 0. N guarded.
__global__ __launch_bounds__(256, 2) void gemm_nt_mfma(
    const float* __restrict__ A, const float* __restrict__ W,
    float* __restrict__ C, int M, int N, int K,
    int lda, int ldw, int ldc, int epi)
{
  __shared__ __align__(16) __bf16 AsH[TM * TK];
  __shared__ __align__(16) __bf16 AsL[TM * TK];
  __shared__ __align__(16) __bf16 BsH[TM * TK];
  __shared__ __align__(16) __bf16 BsL[TM * TK];

  const int tid = threadIdx.x;
  const int lane = tid & 63;
  const int laneL = lane & 15;       // frag row/col within 16
  const int laneH = lane >> 4;       // k-group (0..3) and C row-group
  const int wave = tid >> 6;
  const int wm = wave >> 1;          // 0..1
  const int wn = wave & 1;           // 0..1
  const int row0 = blockIdx.y * TM;
  const int col0 = blockIdx.x * TN;

  // staging: thread -> (row, k-half)
  const int srow = tid >> 1;         // 0..127
  const int skh = tid & 1;           // 0..1 (16 floats each)
  const int ssw = (srow >> 1) & 3;   // XOR swizzle of 16B slots
  const int so0 = srow * TK + (((skh * 2 + 0) ^ ssw) << 3);
  const int so1 = srow * TK + (((skh * 2 + 1) ^ ssw) << 3);

  f32x4 acc[4][4] = {};

  for (int k0 = 0; k0 < K; k0 += TK) {
    // ---- stage A tile (rows always in range: M % 128 == 0) ----
    {
      float f[16];
      const float* g = A + (size_t)(row0 + srow) * lda + k0 + skh * 16;
#pragma unroll
      for (int i = 0; i < 4; i++) *(f32x4*)&f[i * 4] = *(const f32x4*)&g[i * 4];
      bf16x8 h0, l0, h1, l1;
      cvt_hilo(f, h0, l0);
      cvt_hilo(f + 8, h1, l1);
      *(bf16x8*)&AsH[so0] = h0; *(bf16x8*)&AsL[so0] = l0;
      *(bf16x8*)&AsH[so1] = h1; *(bf16x8*)&AsL[so1] = l1;
    }
    // ---- stage B tile (weight rows guarded against N) ----
    {
      float f[16] = {0.f, 0.f, 0.f, 0.f, 0.f, 0.f, 0.f, 0.f,
                     0.f, 0.f, 0.f, 0.f, 0.f, 0.f, 0.f, 0.f};
      const int wr = col0 + srow;
      if (wr < N) {
        const float* g = W + (size_t)wr * ldw + k0 + skh * 16;
#pragma unroll
        for (int i = 0; i < 4; i++) *(f32x4*)&f[i * 4] = *(const f32x4*)&g[i * 4];
      }
      bf16x8 h0, l0, h1, l1;
      cvt_hilo(f, h0, l0);
      cvt_hilo(f + 8, h1, l1);
      *(bf16x8*)&BsH[so0] = h0; *(bf16x8*)&BsL[so0] = l0;
      *(bf16x8*)&BsH[so1] = h1; *(bf16x8*)&BsL[so1] = l1;
    }
    __syncthreads();

    // ---- fragments ----
    bf16x8 aH[4], aL[4], bH[4], bL[4];
#pragma unroll
    for (int i = 0; i < 4; i++) {
      int r = wm * 64 + i * 16 + laneL;
      int off = r * TK + ((laneH ^ ((r >> 1) & 3)) << 3);
      aH[i] = *(const bf16x8*)&AsH[off];
      aL[i] = *(const bf16x8*)&AsL[off];
    }
#pragma unroll
    for (int j = 0; j < 4; j++) {
      int r = wn * 64 + j * 16 + laneL;
      int off = r * TK + ((laneH ^ ((r >> 1) & 3)) << 3);
      bH[j] = *(const bf16x8*)&BsH[off];
      bL[j] = *(const bf16x8*)&BsL[off];
    }
#pragma unroll
    for (int i = 0; i < 4; i++)
#pragma unroll
      for (int j = 0; j < 4; j++) {
        acc[i][j] = __builtin_amdgcn_mfma_f32_16x16x32_bf16(aH[i], bH[j], acc[i][j], 0, 0, 0);
        acc[i][j] = __builtin_amdgcn_mfma_f32_16x16x32_bf16(aH[i], bL[j], acc[i][j], 0, 0, 0);
        acc[i][j] = __builtin_amdgcn_mfma_f32_16x16x32_bf16(aL[i], bH[j], acc[i][j], 0, 0, 0);
      }
    __syncthreads();
  }

  // ---- epilogue: C/D frag mapping col = lane&15, row = (lane>>4)*4 + r ----
#pragma unroll
  for (int i = 0; i < 4; i++) {
    int rr = row0 + wm * 64 + i * 16 + laneH * 4;
#pragma unroll
    for (int j = 0; j < 4; j++) {
      int cc = col0 + wn * 64 + j * 16 + laneL;
      if (cc < N) {
#pragma unroll
        for (int r = 0; r < 4; r++) {
          float v = acc[i][j][r];
          if (epi == 1) v = (v > 20.f) ? v : log1pf(expf(v));
          C[(size_t)(rr + r) * ldc + cc] = v;
        }
      }
    }
  }
}

// Depthwise causal conv (K=4) + bias + silu.
// xz: (4096 x 4096), x_pre = cols [0,2048). Output x: (4096 x 2048).
__global__ __launch_bounds__(256) void conv_silu_k(
    const float* __restrict__ xz, const float* __restrict__ conv_w,
    const float* __restrict__ conv_b, float* __restrict__ x)
{
  const int d = blockIdx.x * 256 + threadIdx.x;   // 0..2047
  const int row = blockIdx.y;                     // b*1024 + l
  const int l = row & 1023;
  const float4 w = ((const float4*)conv_w)[d];
  float acc = conv_b[d];
  const float* base = xz + (size_t)row * 4096 + d;
  if (l >= 3) acc = fmaf(base[-3 * 4096], w.x, acc);
  if (l >= 2) acc = fmaf(base[-2 * 4096], w.y, acc);
  if (l >= 1) acc = fmaf(base[-1 * 4096], w.z, acc);
  acc = fmaf(base[0], w.w, acc);
  x[(size_t)row * 2048 + d] = acc / (1.f + expf(-acc));
}

// Selective scan. Each thread: one d channel x 4 of the 16 states.
#define SDB 32   // d-channels per block
#define LCH 16   // timesteps per chunk

__global__ __launch_bounds__(128) void scan_k(
    const float* __restrict__ delta,
    const float* __restrict__ x,
    const float* __restrict__ xz,     // z at cols [2048,4096)
    const float* __restrict__ x_dbl,  // (4096 x 96): dt|B|C
    const float* __restrict__ A_log,
    const float* __restrict__ Dvec,
    float* __restrict__ out)          // == delta (in-place)
{
  __shared__ __align__(16) float sdelta[LCH][SDB];
  __shared__ __align__(16) float sx[LCH][SDB];
  __shared__ __align__(16) float sz[LCH][SDB];
  __shared__ __align__(16) float sB[LCH][16];
  __shared__ __align__(16) float sC[LCH][16];
  __shared__ __align__(16) float sOut[LCH][SDB];

  const int tid = threadIdx.x;     // 0..127
  const int dl = tid >> 2;         // 0..31
  const int ng = tid & 3;          // 0..3 (4 states each)
  const int d0 = blockIdx.x * SDB;
  const int b = blockIdx.y;
  const int d = d0 + dl;
  const size_t brow = (size_t)b * 1024;

  float Areg[4];
#pragma unroll
  for (int i = 0; i < 4; i++) Areg[i] = -expf(A_log[d * 16 + ng * 4 + i]);
  const float Dd = Dvec[d];
  float h[4] = {0.f, 0.f, 0.f, 0.f};

  for (int c0 = 0; c0 < 1024; c0 += LCH) {
#pragma unroll
    for (int i = 0; i < 4; i++) {
      int e = tid + i * 128;            // 0..511
      int lr = e >> 5, dd = e & 31;
      size_t row = brow + c0 + lr;
      sdelta[lr][dd] = delta[row * 2048 + d0 + dd];
      sx[lr][dd] = x[row * 2048 + d0 + dd];
      sz[lr][dd] = xz[row * 4096 + 2048 + d0 + dd];
    }
#pragma unroll
    for (int i = 0; i < 2; i++) {
      int e = tid + i * 128;            // 0..255
      int lr = e >> 4, nn = e & 15;
      size_t row = brow + c0 + lr;
      sB[lr][nn] = x_dbl[row * 96 + 64 + nn];
      sC[lr][nn] = x_dbl[row * 96 + 80 + nn];
    }
    __syncthreads();
#pragma unroll
    for (int s = 0; s < LCH; s++) {
      float dlt = sdelta[s][dl];
      float xv = sx[s][dl];
      float dx = dlt * xv;
      const float4 Bv = *(const float4*)&sB[s][ng * 4];
      const float4 Cv = *(const float4*)&sC[s][ng * 4];
      float acc;
      h[0] = expf(dlt * Areg[0]) * h[0] + dx * Bv.x; acc  = h[0] * Cv.x;
      h[1] = expf(dlt * Areg[1]) * h[1] + dx * Bv.y; acc += h[1] * Cv.y;
      h[2] = expf(dlt * Areg[2]) * h[2] + dx * Bv.z; acc += h[2] * Cv.z;
      h[3] = expf(dlt * Areg[3]) * h[3] + dx * Bv.w; acc += h[3] * Cv.w;
      acc += __shfl_xor(acc, 1);
      acc += __shfl_xor(acc, 2);
      if (ng == 0) {
        float zv = sz[s][dl];
        float silu_z = zv / (1.f + expf(-zv));
        sOut[s][dl] = (acc + xv * Dd) * silu_z;
      }
    }
    __syncthreads();
#pragma unroll
    for (int i = 0; i < 4; i++) {
      int e = tid + i * 128;
      int lr = e >> 5, dd = e & 31;
      size_t row = brow + c0 + lr;
      out[row * 2048 + d0 + dd] = sOut[lr][dd];
    }
  }
}

extern "C" void kernel_launch(void* const* d_in, const int* in_sizes, int n_in,
                              void* d_out, int out_size, void* d_ws, size_t ws_size,
                              hipStream_t stream)
{
  const float* hidden     = (const float*)d_in[0];  // (4,1024,1024)
  const float* in_proj_w  = (const float*)d_in[1];  // (4096,1024)
  const float* conv_w     = (const float*)d_in[2];  // (2048,4)
  const float* conv_b     = (const float*)d_in[3];  // (2048,)
  const float* x_proj_w   = (const float*)d_in[4];  // (96,2048)
  const float* dt_proj_w  = (const float*)d_in[5];  // (2048,64)
  const float* A_log      = (const float*)d_in[6];  // (2048,16)
  const float* Dvec       = (const float*)d_in[7];  // (2048,)
  const float* out_proj_w = (const float*)d_in[8];  // (1024,2048)
  float* out = (float*)d_out;                       // (4,1024,1024)

  float* xz    = (float*)d_ws;                  // 4096 x 4096  (x_pre | z)
  float* x     = xz + (size_t)4096 * 4096;      // 4096 x 2048
  float* x_dbl = x + (size_t)4096 * 2048;       // 4096 x 96
  float* delta = x_dbl + (size_t)4096 * 96;     // 4096 x 2048 (also scan out)

  // xz = hidden @ in_proj_w^T   (M=4096, N=4096, K=1024)
  gemm_nt_mfma<<<dim3(32, 32), 256, 0, stream>>>(hidden, in_proj_w, xz,
                                                 4096, 4096, 1024, 1024, 1024, 4096, 0);
  // x = silu(depthwise_conv(x_pre) + conv_b)
  conv_silu_k<<<dim3(8, 4096), 256, 0, stream>>>(xz, conv_w, conv_b, x);
  // x_dbl = x @ x_proj_w^T      (M=4096, N=96, K=2048)
  gemm_nt_mfma<<<dim3(1, 32), 256, 0, stream>>>(x, x_proj_w, x_dbl,
                                                4096, 96, 2048, 2048, 2048, 96, 0);
  // delta = softplus(dt @ dt_proj_w^T)  (M=4096, N=2048, K=64)
  gemm_nt_mfma<<<dim3(16, 32), 256, 0, stream>>>(x_dbl, dt_proj_w, delta,
                                                 4096, 2048, 64, 96, 64, 2048, 1);
  // selective scan + epilogue, in-place over delta
  scan_k<<<dim3(64, 4), 128, 0, stream>>>(delta, x, xz, x_dbl, A_log, Dvec, delta);
  // out = scan_out @ out_proj_w^T  (M=4096, N=1024, K=2048)
  gemm_nt_mfma<<<dim3(8, 32), 256, 0, stream>>>(delta, out_proj_w, out,
                                                4096, 1024, 2048, 2048, 2048, 1024, 0);
}

// Round 3
// 494.569 us; speedup vs baseline: 3.2909x; 1.5100x over previous
//
#include <hip/hip_runtime.h>
#include <math.h>

// ---------------------------------------------------------------------------
// Mamba block forward. b=4, l=1024, dm=1024, di=2048, n=16, r=64.
// GEMMs on MFMA via bf16 hi/lo split (3 MFMA per product).
// Selective scan: chunked 3-phase (32 chunks x 32 steps) for parallelism.
// ---------------------------------------------------------------------------

typedef __bf16 bf16x8 __attribute__((ext_vector_type(8)));
typedef float f32x4 __attribute__((ext_vector_type(4)));

#define TM 128
#define TN 128
#define TK 32

__device__ __forceinline__ void cvt_hilo(const float* f, bf16x8& h, bf16x8& l) {
#pragma unroll
  for (int i = 0; i < 8; i++) {
    float v = f[i];
    __bf16 hh = (__bf16)v;
    h[i] = hh;
    l[i] = (__bf16)(v - (float)hh);
  }
}

// NT GEMM on MFMA: A (M x K, lda) f32, W (N x K, ldw) f32, C (M x N, ldc) f32.
// epi: 0 = none, 1 = softplus. M % 128 == 0, K % 32 == 0. N guarded.
__global__ __launch_bounds__(256, 2) void gemm_nt_mfma(
    const float* __restrict__ A, const float* __restrict__ W,
    float* __restrict__ C, int M, int N, int K,
    int lda, int ldw, int ldc, int epi)
{
  __shared__ __align__(16) __bf16 AsH[TM * TK];
  __shared__ __align__(16) __bf16 AsL[TM * TK];
  __shared__ __align__(16) __bf16 BsH[TM * TK];
  __shared__ __align__(16) __bf16 BsL[TM * TK];

  const int tid = threadIdx.x;
  const int lane = tid & 63;
  const int laneL = lane & 15;
  const int laneH = lane >> 4;
  const int wave = tid >> 6;
  const int wm = wave >> 1;
  const int wn = wave & 1;
  const int row0 = blockIdx.y * TM;
  const int col0 = blockIdx.x * TN;

  const int srow = tid >> 1;
  const int skh = tid & 1;
  const int ssw = (srow >> 1) & 3;
  const int so0 = srow * TK + (((skh * 2 + 0) ^ ssw) << 3);
  const int so1 = srow * TK + (((skh * 2 + 1) ^ ssw) << 3);

  f32x4 acc[4][4] = {};

  for (int k0 = 0; k0 < K; k0 += TK) {
    {
      float f[16];
      const float* g = A + (size_t)(row0 + srow) * lda + k0 + skh * 16;
#pragma unroll
      for (int i = 0; i < 4; i++) *(f32x4*)&f[i * 4] = *(const f32x4*)&g[i * 4];
      bf16x8 h0, l0, h1, l1;
      cvt_hilo(f, h0, l0);
      cvt_hilo(f + 8, h1, l1);
      *(bf16x8*)&AsH[so0] = h0; *(bf16x8*)&AsL[so0] = l0;
      *(bf16x8*)&AsH[so1] = h1; *(bf16x8*)&AsL[so1] = l1;
    }
    {
      float f[16] = {0.f, 0.f, 0.f, 0.f, 0.f, 0.f, 0.f, 0.f,
                     0.f, 0.f, 0.f, 0.f, 0.f, 0.f, 0.f, 0.f};
      const int wr = col0 + srow;
      if (wr < N) {
        const float* g = W + (size_t)wr * ldw + k0 + skh * 16;
#pragma unroll
        for (int i = 0; i < 4; i++) *(f32x4*)&f[i * 4] = *(const f32x4*)&g[i * 4];
      }
      bf16x8 h0, l0, h1, l1;
      cvt_hilo(f, h0, l0);
      cvt_hilo(f + 8, h1, l1);
      *(bf16x8*)&BsH[so0] = h0; *(bf16x8*)&BsL[so0] = l0;
      *(bf16x8*)&BsH[so1] = h1; *(bf16x8*)&BsL[so1] = l1;
    }
    __syncthreads();

    bf16x8 aH[4], aL[4], bH[4], bL[4];
#pragma unroll
    for (int i = 0; i < 4; i++) {
      int r = wm * 64 + i * 16 + laneL;
      int off = r * TK + ((laneH ^ ((r >> 1) & 3)) << 3);
      aH[i] = *(const bf16x8*)&AsH[off];
      aL[i] = *(const bf16x8*)&AsL[off];
    }
#pragma unroll
    for (int j = 0; j < 4; j++) {
      int r = wn * 64 + j * 16 + laneL;
      int off = r * TK + ((laneH ^ ((r >> 1) & 3)) << 3);
      bH[j] = *(const bf16x8*)&BsH[off];
      bL[j] = *(const bf16x8*)&BsL[off];
    }
#pragma unroll
    for (int i = 0; i < 4; i++)
#pragma unroll
      for (int j = 0; j < 4; j++) {
        acc[i][j] = __builtin_amdgcn_mfma_f32_16x16x32_bf16(aH[i], bH[j], acc[i][j], 0, 0, 0);
        acc[i][j] = __builtin_amdgcn_mfma_f32_16x16x32_bf16(aH[i], bL[j], acc[i][j], 0, 0, 0);
        acc[i][j] = __builtin_amdgcn_mfma_f32_16x16x32_bf16(aL[i], bH[j], acc[i][j], 0, 0, 0);
      }
    __syncthreads();
  }

#pragma unroll
  for (int i = 0; i < 4; i++) {
    int rr = row0 + wm * 64 + i * 16 + laneH * 4;
#pragma unroll
    for (int j = 0; j < 4; j++) {
      int cc = col0 + wn * 64 + j * 16 + laneL;
      if (cc < N) {
#pragma unroll
        for (int r = 0; r < 4; r++) {
          float v = acc[i][j][r];
          if (epi == 1) v = (v > 20.f) ? v : log1pf(expf(v));
          C[(size_t)(rr + r) * ldc + cc] = v;
        }
      }
    }
  }
}

// Depthwise causal conv (K=4) + bias + silu.
__global__ __launch_bounds__(256) void conv_silu_k(
    const float* __restrict__ xz, const float* __restrict__ conv_w,
    const float* __restrict__ conv_b, float* __restrict__ x)
{
  const int d = blockIdx.x * 256 + threadIdx.x;
  const int row = blockIdx.y;
  const int l = row & 1023;
  const float4 w = ((const float4*)conv_w)[d];
  float acc = conv_b[d];
  const float* base = xz + (size_t)row * 4096 + d;
  if (l >= 3) acc = fmaf(base[-3 * 4096], w.x, acc);
  if (l >= 2) acc = fmaf(base[-2 * 4096], w.y, acc);
  if (l >= 1) acc = fmaf(base[-1 * 4096], w.z, acc);
  acc = fmaf(base[0], w.w, acc);
  x[(size_t)row * 2048 + d] = acc / (1.f + expf(-acc));
}

// ---------------------------------------------------------------------------
// Chunked selective scan: L=1024 -> NCH=32 chunks x LC=32 steps.
//   h_t = exp(delta_t*A) h_{t-1} + delta_t*x_t*B_t  (per state)
//   chunk a-product = exp(A * sum(delta))  -> only sum(delta) needed.
// S1: per-chunk Q (zero-init recurrence) + sum(delta).
// S2: serial 32-step inter-chunk scan; Hstart written in place over Q.
// S3: re-run chunk from Hstart, y + fused epilogue, in-place over delta.
// ---------------------------------------------------------------------------
#define NCHK 32
#define LC   32
#define DB   64
#define LOG2E 1.44269504f

__global__ __launch_bounds__(256) void scan_chunk1(
    const float* __restrict__ delta, const float* __restrict__ x,
    const float* __restrict__ x_dbl, const float* __restrict__ A_log,
    float* __restrict__ Bacc, float* __restrict__ sdsum)
{
  __shared__ __align__(16) float sdel[LC][DB];
  __shared__ __align__(16) float sx[LC][DB];
  __shared__ __align__(16) float sB[LC][16];

  const int tid = threadIdx.x;
  const int dl = tid >> 2;           // 0..63
  const int ng = tid & 3;            // 0..3
  const int d0 = blockIdx.x * DB;
  const int c = blockIdx.y, b = blockIdx.z;
  const int d = d0 + dl;
  const size_t row0 = (size_t)b * 1024 + c * LC;

  float a2[4];
#pragma unroll
  for (int i = 0; i < 4; i++) a2[i] = -expf(A_log[d * 16 + ng * 4 + i]) * LOG2E;

#pragma unroll
  for (int i = 0; i < 2; i++) {
    int f = tid + i * 256;           // 0..511 float4 units
    int lr = f >> 4, c4 = (f & 15) * 4;
    size_t g = (row0 + lr) * 2048 + d0 + c4;
    *(float4*)&sdel[lr][c4] = *(const float4*)&delta[g];
    *(float4*)&sx[lr][c4]   = *(const float4*)&x[g];
  }
  if (tid < 128) {
    int lr = tid >> 2, n4 = (tid & 3) * 4;
    *(float4*)&sB[lr][n4] = *(const float4*)&x_dbl[(row0 + lr) * 96 + 64 + n4];
  }
  __syncthreads();

  float q0 = 0.f, q1 = 0.f, q2 = 0.f, q3 = 0.f, sd = 0.f;
#pragma unroll
  for (int t = 0; t < LC; t++) {
    float dlt = sdel[t][dl];
    float dx = dlt * sx[t][dl];
    const float4 Bv = *(const float4*)&sB[t][ng * 4];
    q0 = exp2f(dlt * a2[0]) * q0 + dx * Bv.x;
    q1 = exp2f(dlt * a2[1]) * q1 + dx * Bv.y;
    q2 = exp2f(dlt * a2[2]) * q2 + dx * Bv.z;
    q3 = exp2f(dlt * a2[3]) * q3 + dx * Bv.w;
    sd += dlt;
  }
  size_t o = ((size_t)(b * NCHK + c) * 2048 + d) * 16 + ng * 4;
  float4 qv = make_float4(q0, q1, q2, q3);
  *(float4*)&Bacc[o] = qv;
  if (ng == 0) sdsum[(size_t)(b * NCHK + c) * 2048 + d] = sd;
}

// Inter-chunk scan. BaccH: in = Q, out = Hstart (chunk start state).
__global__ __launch_bounds__(256) void scan_chunk2(
    const float* __restrict__ A_log, const float* __restrict__ sdsum,
    float* __restrict__ BaccH)
{
  const int g = blockIdx.x * 256 + threadIdx.x;   // 0..32767
  const int ng = g & 3;
  const int d = (g >> 2) & 2047;
  const int b = g >> 13;
  float a2[4];
#pragma unroll
  for (int i = 0; i < 4; i++) a2[i] = -expf(A_log[d * 16 + ng * 4 + i]) * LOG2E;
  float h0 = 0.f, h1 = 0.f, h2 = 0.f, h3 = 0.f;
#pragma unroll 4
  for (int c = 0; c < NCHK; c++) {
    size_t o = ((size_t)(b * NCHK + c) * 2048 + d) * 16 + ng * 4;
    const float4 Q = *(const float4*)&BaccH[o];
    const float sd = sdsum[(size_t)(b * NCHK + c) * 2048 + d];
    float4 hv = make_float4(h0, h1, h2, h3);
    *(float4*)&BaccH[o] = hv;          // start state for chunk c
    h0 = exp2f(sd * a2[0]) * h0 + Q.x;
    h1 = exp2f(sd * a2[1]) * h1 + Q.y;
    h2 = exp2f(sd * a2[2]) * h2 + Q.z;
    h3 = exp2f(sd * a2[3]) * h3 + Q.w;
  }
}

__global__ __launch_bounds__(256) void scan_chunk3(
    const float* __restrict__ delta, const float* __restrict__ x,
    const float* __restrict__ xz, const float* __restrict__ x_dbl,
    const float* __restrict__ A_log, const float* __restrict__ Dvec,
    const float* __restrict__ Hstart, float* __restrict__ out)
{
  __shared__ __align__(16) float sdel[LC][DB];
  __shared__ __align__(16) float sx[LC][DB];
  __shared__ __align__(16) float szo[LC][DB];   // z in, result out
  __shared__ __align__(16) float sB[LC][16];
  __shared__ __align__(16) float sC[LC][16];

  const int tid = threadIdx.x;
  const int dl = tid >> 2;
  const int ng = tid & 3;
  const int d0 = blockIdx.x * DB;
  const int c = blockIdx.y, b = blockIdx.z;
  const int d = d0 + dl;
  const size_t row0 = (size_t)b * 1024 + c * LC;

  float a2[4];
#pragma unroll
  for (int i = 0; i < 4; i++) a2[i] = -expf(A_log[d * 16 + ng * 4 + i]) * LOG2E;
  const float Dd = Dvec[d];

#pragma unroll
  for (int i = 0; i < 2; i++) {
    int f = tid + i * 256;
    int lr = f >> 4, c4 = (f & 15) * 4;
    size_t g = (row0 + lr) * 2048 + d0 + c4;
    *(float4*)&sdel[lr][c4] = *(const float4*)&delta[g];
    *(float4*)&sx[lr][c4]   = *(const float4*)&x[g];
    *(float4*)&szo[lr][c4]  = *(const float4*)&xz[(row0 + lr) * 4096 + 2048 + d0 + c4];
  }
  {
    int which = tid >> 7;              // 0: B, 1: C
    int f = tid & 127;
    int lr = f >> 2, n4 = (f & 3) * 4;
    float4 v = *(const float4*)&x_dbl[(row0 + lr) * 96 + 64 + which * 16 + n4];
    if (which == 0) *(float4*)&sB[lr][n4] = v;
    else            *(float4*)&sC[lr][n4] = v;
  }
  __syncthreads();

  size_t ho = ((size_t)(b * NCHK + c) * 2048 + d) * 16 + ng * 4;
  const float4 hv = *(const float4*)&Hstart[ho];
  float h0 = hv.x, h1 = hv.y, h2 = hv.z, h3 = hv.w;

#pragma unroll
  for (int t = 0; t < LC; t++) {
    float dlt = sdel[t][dl];
    float xv = sx[t][dl];
    float dx = dlt * xv;
    const float4 Bv = *(const float4*)&sB[t][ng * 4];
    const float4 Cv = *(const float4*)&sC[t][ng * 4];
    float acc;
    h0 = exp2f(dlt * a2[0]) * h0 + dx * Bv.x; acc  = h0 * Cv.x;
    h1 = exp2f(dlt * a2[1]) * h1 + dx * Bv.y; acc += h1 * Cv.y;
    h2 = exp2f(dlt * a2[2]) * h2 + dx * Bv.z; acc += h2 * Cv.z;
    h3 = exp2f(dlt * a2[3]) * h3 + dx * Bv.w; acc += h3 * Cv.w;
    acc += __shfl_xor(acc, 1);
    acc += __shfl_xor(acc, 2);
    if (ng == 0) {
      float zv = szo[t][dl];
      szo[t][dl] = (acc + xv * Dd) * (zv / (1.f + expf(-zv)));
    }
  }
  __syncthreads();
#pragma unroll
  for (int i = 0; i < 2; i++) {
    int f = tid + i * 256;
    int lr = f >> 4, c4 = (f & 15) * 4;
    *(float4*)&out[(row0 + lr) * 2048 + d0 + c4] = *(const float4*)&szo[lr][c4];
  }
}

extern "C" void kernel_launch(void* const* d_in, const int* in_sizes, int n_in,
                              void* d_out, int out_size, void* d_ws, size_t ws_size,
                              hipStream_t stream)
{
  const float* hidden     = (const float*)d_in[0];
  const float* in_proj_w  = (const float*)d_in[1];
  const float* conv_w     = (const float*)d_in[2];
  const float* conv_b     = (const float*)d_in[3];
  const float* x_proj_w   = (const float*)d_in[4];
  const float* dt_proj_w  = (const float*)d_in[5];
  const float* A_log      = (const float*)d_in[6];
  const float* Dvec       = (const float*)d_in[7];
  const float* out_proj_w = (const float*)d_in[8];
  float* out = (float*)d_out;

  float* xz    = (float*)d_ws;                  // 4096 x 4096
  float* x     = xz + (size_t)4096 * 4096;      // 4096 x 2048
  float* x_dbl = x + (size_t)4096 * 2048;       // 4096 x 96
  float* delta = x_dbl + (size_t)4096 * 96;     // 4096 x 2048 (scan out)
  float* Bacc  = delta + (size_t)4096 * 2048;   // 4*32 x 2048 x 16 (then Hstart)
  float* sdsum = Bacc + (size_t)4 * NCHK * 2048 * 16;  // 4*32 x 2048

  // xz = hidden @ in_proj_w^T   (M=4096, N=4096, K=1024)
  gemm_nt_mfma<<<dim3(32, 32), 256, 0, stream>>>(hidden, in_proj_w, xz,
                                                 4096, 4096, 1024, 1024, 1024, 4096, 0);
  // x = silu(depthwise_conv(x_pre) + conv_b)
  conv_silu_k<<<dim3(8, 4096), 256, 0, stream>>>(xz, conv_w, conv_b, x);
  // x_dbl = x @ x_proj_w^T      (M=4096, N=96, K=2048)
  gemm_nt_mfma<<<dim3(1, 32), 256, 0, stream>>>(x, x_proj_w, x_dbl,
                                                4096, 96, 2048, 2048, 2048, 96, 0);
  // delta = softplus(dt @ dt_proj_w^T)  (M=4096, N=2048, K=64)
  gemm_nt_mfma<<<dim3(16, 32), 256, 0, stream>>>(x_dbl, dt_proj_w, delta,
                                                 4096, 2048, 64, 96, 64, 2048, 1);
  // chunked selective scan
  scan_chunk1<<<dim3(32, NCHK, 4), 256, 0, stream>>>(delta, x, x_dbl, A_log, Bacc, sdsum);
  scan_chunk2<<<dim3(128), 256, 0, stream>>>(A_log, sdsum, Bacc);
  scan_chunk3<<<dim3(32, NCHK, 4), 256, 0, stream>>>(delta, x, xz, x_dbl, A_log, Dvec,
                                                     Bacc, delta);
  // out = scan_out @ out_proj_w^T  (M=4096, N=1024, K=2048)
  gemm_nt_mfma<<<dim3(8, 32), 256, 0, stream>>>(delta, out_proj_w, out,
                                                4096, 1024, 2048, 2048, 2048, 1024, 0);
}

// Round 5
// 388.430 us; speedup vs baseline: 4.1902x; 1.2733x over previous
//
#include <hip/hip_runtime.h>
#include <math.h>

// ---------------------------------------------------------------------------
// Mamba block forward. b=4, l=1024, dm=1024, di=2048, n=16, r=64.
// GEMMs: pure-bf16 MFMA (hi/lo split, 3 MFMA/product), inputs pre-converted.
// Staging via global_load_lds dwordx4 with XOR slot swizzle (2-way banks).
// Scan: chunked 3-phase (32 chunks x 32 steps).
// R4 bug: reduce_oproj grid was 1024 (wrote only batch 0); must be 4096.
// ---------------------------------------------------------------------------

typedef __bf16 bf16x8 __attribute__((ext_vector_type(8)));
typedef __bf16 bf16x4 __attribute__((ext_vector_type(4)));
typedef float f32x4 __attribute__((ext_vector_type(4)));

__device__ __forceinline__ void gload16(const void* g, void* lds) {
  __builtin_amdgcn_global_load_lds((const __attribute__((address_space(1))) void*)g,
                                   (__attribute__((address_space(3))) void*)lds,
                                   16, 0, 0);
}

// ---------------- f32 -> bf16 hi/lo conversion helpers ----------------
__device__ __forceinline__ void hilo4(float4 v, bf16x4& h, bf16x4& l) {
  h[0] = (__bf16)v.x; l[0] = (__bf16)(v.x - (float)h[0]);
  h[1] = (__bf16)v.y; l[1] = (__bf16)(v.y - (float)h[1]);
  h[2] = (__bf16)v.z; l[2] = (__bf16)(v.z - (float)h[2]);
  h[3] = (__bf16)v.w; l[3] = (__bf16)(v.w - (float)h[3]);
}

__global__ __launch_bounds__(256) void cvt_hilo_k(
    const float* __restrict__ s, __bf16* __restrict__ H,
    __bf16* __restrict__ L, int n4)
{
  int i = blockIdx.x * 256 + threadIdx.x;
  if (i >= n4) return;
  float4 v = ((const float4*)s)[i];
  bf16x4 h, l;
  hilo4(v, h, l);
  ((bf16x4*)H)[i] = h;
  ((bf16x4*)L)[i] = l;
}

// ---------------------------------------------------------------------------
// NT GEMM, pure bf16 hi/lo: C = (Ah+Al)(Bh+Bl)^T ~ AhBh + AhBl + AlBh.
// A: (M x K) bf16 pair, lda. B: (N x K) bf16 pair, ldb. C f32, ldc.
// Tile 128x128, TK=32, 4 waves (each stages one of the 4 LDS tiles).
// grid (N/128, M/128, S): z splits K into segments of kseg; partial C for
// z-segment s goes to C + s*(gridDim.y*128*ldc).  epi: 0 none, 1 softplus.
// LDS slot swizzle: physical slot p holds logical k-slot p ^ ((row>>1)&3),
// applied on the global source address (gload_lds writes linearly).
// ---------------------------------------------------------------------------
__global__ __launch_bounds__(256, 2) void gemm3(
    const __bf16* __restrict__ Ah, const __bf16* __restrict__ Al,
    const __bf16* __restrict__ Bh, const __bf16* __restrict__ Bl,
    float* __restrict__ C, int lda, int ldb, int ldc, int kseg, int epi)
{
  __shared__ __align__(16) __bf16 sAh[128 * 32];
  __shared__ __align__(16) __bf16 sAl[128 * 32];
  __shared__ __align__(16) __bf16 sBh[128 * 32];
  __shared__ __align__(16) __bf16 sBl[128 * 32];

  const int tid = threadIdx.x;
  const int lane = tid & 63;
  const int laneL = lane & 15;
  const int laneH = lane >> 4;
  const int wave = tid >> 6;
  const int wm = wave >> 1;
  const int wn = wave & 1;
  const int row0 = blockIdx.y * 128;
  const int col0 = blockIdx.x * 128;
  const int k0base = blockIdx.z * kseg;

  // each wave stages one tile
  const __bf16* src = (wave == 0) ? Ah : (wave == 1) ? Al : (wave == 2) ? Bh : Bl;
  const int srcLd = (wave < 2) ? lda : ldb;
  const int srcRow0 = (wave < 2) ? row0 : col0;
  __bf16* dst = (wave == 0) ? sAh : (wave == 1) ? sAl : (wave == 2) ? sBh : sBl;
  const int lr = lane >> 2;          // 0..15 row within 16-row group
  const int ls = lane & 3;           // 0..3 physical 16B slot
  const int ksl = (ls ^ ((lr >> 1) & 3)) * 8;  // swizzled logical k-offset (elems)

  const int rsw = (laneL >> 1) & 3;  // read-side swizzle
  f32x4 acc[4][4] = {};

  for (int k0 = k0base; k0 < k0base + kseg; k0 += 32) {
    const __bf16* g = src + (size_t)(srcRow0 + lr) * srcLd + k0 + ksl;
#pragma unroll
    for (int i = 0; i < 8; i++)
      gload16(g + (size_t)i * 16 * srcLd, dst + i * 512 + lane * 8);
    __syncthreads();

    bf16x8 ah[4], al[4], bh[4], bl[4];
#pragma unroll
    for (int i = 0; i < 4; i++) {
      int off = (wm * 64 + i * 16 + laneL) * 32 + ((laneH ^ rsw) << 3);
      ah[i] = *(const bf16x8*)&sAh[off];
      al[i] = *(const bf16x8*)&sAl[off];
    }
#pragma unroll
    for (int j = 0; j < 4; j++) {
      int off = (wn * 64 + j * 16 + laneL) * 32 + ((laneH ^ rsw) << 3);
      bh[j] = *(const bf16x8*)&sBh[off];
      bl[j] = *(const bf16x8*)&sBl[off];
    }
#pragma unroll
    for (int i = 0; i < 4; i++)
#pragma unroll
      for (int j = 0; j < 4; j++) {
        acc[i][j] = __builtin_amdgcn_mfma_f32_16x16x32_bf16(ah[i], bh[j], acc[i][j], 0, 0, 0);
        acc[i][j] = __builtin_amdgcn_mfma_f32_16x16x32_bf16(ah[i], bl[j], acc[i][j], 0, 0, 0);
        acc[i][j] = __builtin_amdgcn_mfma_f32_16x16x32_bf16(al[i], bh[j], acc[i][j], 0, 0, 0);
      }
    __syncthreads();
  }

  float* Cz = C + (size_t)blockIdx.z * gridDim.y * 128 * ldc;
#pragma unroll
  for (int i = 0; i < 4; i++) {
    int rr = row0 + wm * 64 + i * 16 + laneH * 4;
#pragma unroll
    for (int j = 0; j < 4; j++) {
      int cc = col0 + wn * 64 + j * 16 + laneL;
#pragma unroll
      for (int r = 0; r < 4; r++) {
        float v = acc[i][j][r];
        if (epi == 1) v = (v > 20.f) ? v : log1pf(expf(v));
        Cz[(size_t)(rr + r) * ldc + cc] = v;
      }
    }
  }
}

// ---------------- split-K reduces ----------------
// x_proj: 8 partials (4096 x 128 each, cols 96..127 from zero-pad B).
// Writes x_dbl f32 (4096 x 96) and dt hi/lo (4096 x 64).
__global__ __launch_bounds__(256) void reduce_xproj(
    const float* __restrict__ part, float* __restrict__ x_dbl,
    __bf16* __restrict__ dth, __bf16* __restrict__ dtl)
{
  int idx = blockIdx.x * 256 + threadIdx.x;   // 0 .. 4096*128-1
  int row = idx >> 7, col = idx & 127;
  float v = 0.f;
#pragma unroll
  for (int s = 0; s < 8; s++) v += part[(size_t)s * 524288 + idx];
  if (col < 96) x_dbl[(size_t)row * 96 + col] = v;
  if (col < 64) {
    __bf16 h = (__bf16)v;
    dth[(size_t)row * 64 + col] = h;
    dtl[(size_t)row * 64 + col] = (__bf16)(v - (float)h);
  }
}

// out_proj: 2 partials (4096 x 1024), sum -> out.  out = 1,048,576 float4.
__global__ __launch_bounds__(256) void reduce_oproj(
    const float* __restrict__ part, float* __restrict__ out)
{
  int i = blockIdx.x * 256 + threadIdx.x;     // 0 .. 4096*1024/4-1
  const float4 a = ((const float4*)part)[i];
  const float4 b = ((const float4*)part)[i + 1048576];
  float4 o = make_float4(a.x + b.x, a.y + b.y, a.z + b.z, a.w + b.w);
  ((float4*)out)[i] = o;
}

// ---------------- depthwise causal conv + bias + silu (+ hi/lo out) --------
__global__ __launch_bounds__(256) void conv_silu_k(
    const float* __restrict__ xz, const float* __restrict__ conv_w,
    const float* __restrict__ conv_b, float* __restrict__ x,
    __bf16* __restrict__ xh, __bf16* __restrict__ xl)
{
  const int d = blockIdx.x * 256 + threadIdx.x;
  const int row = blockIdx.y;
  const int l = row & 1023;
  const float4 w = ((const float4*)conv_w)[d];
  float acc = conv_b[d];
  const float* base = xz + (size_t)row * 4096 + d;
  if (l >= 3) acc = fmaf(base[-3 * 4096], w.x, acc);
  if (l >= 2) acc = fmaf(base[-2 * 4096], w.y, acc);
  if (l >= 1) acc = fmaf(base[-1 * 4096], w.z, acc);
  acc = fmaf(base[0], w.w, acc);
  float s = acc / (1.f + expf(-acc));
  size_t o = (size_t)row * 2048 + d;
  x[o] = s;
  __bf16 h = (__bf16)s;
  xh[o] = h;
  xl[o] = (__bf16)(s - (float)h);
}

// ---------------- chunked selective scan ----------------
#define NCHK 32
#define LC   32
#define DB   64
#define LOG2E 1.44269504f

__global__ __launch_bounds__(256) void scan_chunk1(
    const float* __restrict__ delta, const float* __restrict__ x,
    const float* __restrict__ x_dbl, const float* __restrict__ A_log,
    float* __restrict__ Bacc, float* __restrict__ sdsum)
{
  __shared__ __align__(16) float sdel[LC][DB];
  __shared__ __align__(16) float sx[LC][DB];
  __shared__ __align__(16) float sB[LC][16];

  const int tid = threadIdx.x;
  const int dl = tid >> 2;
  const int ng = tid & 3;
  const int d0 = blockIdx.x * DB;
  const int c = blockIdx.y, b = blockIdx.z;
  const int d = d0 + dl;
  const size_t row0 = (size_t)b * 1024 + c * LC;

  float a2[4];
#pragma unroll
  for (int i = 0; i < 4; i++) a2[i] = -expf(A_log[d * 16 + ng * 4 + i]) * LOG2E;

#pragma unroll
  for (int i = 0; i < 2; i++) {
    int f = tid + i * 256;
    int lr = f >> 4, c4 = (f & 15) * 4;
    size_t g = (row0 + lr) * 2048 + d0 + c4;
    *(float4*)&sdel[lr][c4] = *(const float4*)&delta[g];
    *(float4*)&sx[lr][c4]   = *(const float4*)&x[g];
  }
  if (tid < 128) {
    int lr = tid >> 2, n4 = (tid & 3) * 4;
    *(float4*)&sB[lr][n4] = *(const float4*)&x_dbl[(row0 + lr) * 96 + 64 + n4];
  }
  __syncthreads();

  float q0 = 0.f, q1 = 0.f, q2 = 0.f, q3 = 0.f, sd = 0.f;
#pragma unroll
  for (int t = 0; t < LC; t++) {
    float dlt = sdel[t][dl];
    float dx = dlt * sx[t][dl];
    const float4 Bv = *(const float4*)&sB[t][ng * 4];
    q0 = exp2f(dlt * a2[0]) * q0 + dx * Bv.x;
    q1 = exp2f(dlt * a2[1]) * q1 + dx * Bv.y;
    q2 = exp2f(dlt * a2[2]) * q2 + dx * Bv.z;
    q3 = exp2f(dlt * a2[3]) * q3 + dx * Bv.w;
    sd += dlt;
  }
  size_t o = ((size_t)(b * NCHK + c) * 2048 + d) * 16 + ng * 4;
  *(float4*)&Bacc[o] = make_float4(q0, q1, q2, q3);
  if (ng == 0) sdsum[(size_t)(b * NCHK + c) * 2048 + d] = sd;
}

__global__ __launch_bounds__(256) void scan_chunk2(
    const float* __restrict__ A_log, const float* __restrict__ sdsum,
    float* __restrict__ BaccH)
{
  const int g = blockIdx.x * 256 + threadIdx.x;
  const int ng = g & 3;
  const int d = (g >> 2) & 2047;
  const int b = g >> 13;
  float a2[4];
#pragma unroll
  for (int i = 0; i < 4; i++) a2[i] = -expf(A_log[d * 16 + ng * 4 + i]) * LOG2E;
  float h0 = 0.f, h1 = 0.f, h2 = 0.f, h3 = 0.f;
#pragma unroll 4
  for (int c = 0; c < NCHK; c++) {
    size_t o = ((size_t)(b * NCHK + c) * 2048 + d) * 16 + ng * 4;
    const float4 Q = *(const float4*)&BaccH[o];
    const float sd = sdsum[(size_t)(b * NCHK + c) * 2048 + d];
    *(float4*)&BaccH[o] = make_float4(h0, h1, h2, h3);
    h0 = exp2f(sd * a2[0]) * h0 + Q.x;
    h1 = exp2f(sd * a2[1]) * h1 + Q.y;
    h2 = exp2f(sd * a2[2]) * h2 + Q.z;
    h3 = exp2f(sd * a2[3]) * h3 + Q.w;
  }
}

__global__ __launch_bounds__(256) void scan_chunk3(
    const float* __restrict__ delta, const float* __restrict__ x,
    const float* __restrict__ xz, const float* __restrict__ x_dbl,
    const float* __restrict__ A_log, const float* __restrict__ Dvec,
    const float* __restrict__ Hstart,
    __bf16* __restrict__ yh, __bf16* __restrict__ yl)
{
  __shared__ __align__(16) float sdel[LC][DB];
  __shared__ __align__(16) float sx[LC][DB];
  __shared__ __align__(16) float szo[LC][DB];
  __shared__ __align__(16) float sB[LC][16];
  __shared__ __align__(16) float sC[LC][16];

  const int tid = threadIdx.x;
  const int dl = tid >> 2;
  const int ng = tid & 3;
  const int d0 = blockIdx.x * DB;
  const int c = blockIdx.y, b = blockIdx.z;
  const int d = d0 + dl;
  const size_t row0 = (size_t)b * 1024 + c * LC;

  float a2[4];
#pragma unroll
  for (int i = 0; i < 4; i++) a2[i] = -expf(A_log[d * 16 + ng * 4 + i]) * LOG2E;
  const float Dd = Dvec[d];

#pragma unroll
  for (int i = 0; i < 2; i++) {
    int f = tid + i * 256;
    int lr = f >> 4, c4 = (f & 15) * 4;
    size_t g = (row0 + lr) * 2048 + d0 + c4;
    *(float4*)&sdel[lr][c4] = *(const float4*)&delta[g];
    *(float4*)&sx[lr][c4]   = *(const float4*)&x[g];
    *(float4*)&szo[lr][c4]  = *(const float4*)&xz[(row0 + lr) * 4096 + 2048 + d0 + c4];
  }
  {
    int which = tid >> 7;
    int f = tid & 127;
    int lr = f >> 2, n4 = (f & 3) * 4;
    float4 v = *(const float4*)&x_dbl[(row0 + lr) * 96 + 64 + which * 16 + n4];
    if (which == 0) *(float4*)&sB[lr][n4] = v;
    else            *(float4*)&sC[lr][n4] = v;
  }
  __syncthreads();

  size_t ho = ((size_t)(b * NCHK + c) * 2048 + d) * 16 + ng * 4;
  const float4 hv = *(const float4*)&Hstart[ho];
  float h0 = hv.x, h1 = hv.y, h2 = hv.z, h3 = hv.w;

#pragma unroll
  for (int t = 0; t < LC; t++) {
    float dlt = sdel[t][dl];
    float xv = sx[t][dl];
    float dx = dlt * xv;
    const float4 Bv = *(const float4*)&sB[t][ng * 4];
    const float4 Cv = *(const float4*)&sC[t][ng * 4];
    float acc;
    h0 = exp2f(dlt * a2[0]) * h0 + dx * Bv.x; acc  = h0 * Cv.x;
    h1 = exp2f(dlt * a2[1]) * h1 + dx * Bv.y; acc += h1 * Cv.y;
    h2 = exp2f(dlt * a2[2]) * h2 + dx * Bv.z; acc += h2 * Cv.z;
    h3 = exp2f(dlt * a2[3]) * h3 + dx * Bv.w; acc += h3 * Cv.w;
    acc += __shfl_xor(acc, 1);
    acc += __shfl_xor(acc, 2);
    if (ng == 0) {
      float zv = szo[t][dl];
      szo[t][dl] = (acc + xv * Dd) * (zv / (1.f + expf(-zv)));
    }
  }
  __syncthreads();
#pragma unroll
  for (int i = 0; i < 2; i++) {
    int f = tid + i * 256;
    int lr = f >> 4, c4 = (f & 15) * 4;
    float4 v = *(const float4*)&szo[lr][c4];
    bf16x4 h, l;
    hilo4(v, h, l);
    size_t o = (row0 + lr) * 2048 + d0 + c4;
    *(bf16x4*)&yh[o] = h;
    *(bf16x4*)&yl[o] = l;
  }
}

extern "C" void kernel_launch(void* const* d_in, const int* in_sizes, int n_in,
                              void* d_out, int out_size, void* d_ws, size_t ws_size,
                              hipStream_t stream)
{
  const float* hidden     = (const float*)d_in[0];
  const float* in_proj_w  = (const float*)d_in[1];
  const float* conv_w     = (const float*)d_in[2];
  const float* conv_b     = (const float*)d_in[3];
  const float* x_proj_w   = (const float*)d_in[4];
  const float* dt_proj_w  = (const float*)d_in[5];
  const float* A_log      = (const float*)d_in[6];
  const float* Dvec       = (const float*)d_in[7];
  const float* out_proj_w = (const float*)d_in[8];
  float* out = (float*)d_out;

  // ---- workspace arena (f32 element offsets); aliased regions noted ----
  float* w = (float*)d_ws;
  float* xz    = w;                         // 16,777,216   [gemm1 .. scan3]; later op_part
  float* x     = xz + 16777216;             //  8,388,608   [conv .. scan3]
  float* x_dbl = x + 8388608;               //    393,216   [reduce_xp .. scan3]
  float* dreg  = x_dbl + 393216;            //  8,388,608   hid/inw cvt -> xh/xl -> delta
  float* Breg  = dreg + 8388608;            //  4,194,304   xp_part -> Bacc
  float* sdsum = Breg + 4194304;            //    262,144
  float* Dreg  = sdsum + 262144;            //  8,388,608   yh/yl
  float* wsm   = Dreg + 8388608;            //  2,752,512   small weights

  __bf16* d16   = (__bf16*)dreg;
  __bf16* hid_h = d16;                      // 4,194,304 bf16
  __bf16* hid_l = d16 + 4194304;
  __bf16* inw_h = d16 + 8388608;
  __bf16* inw_l = d16 + 12582912;
  __bf16* xh    = d16;                      // 8,388,608 bf16 (after gemm1)
  __bf16* xl    = d16 + 8388608;
  float*  delta = dreg;                     // f32 (after x_proj)
  float*  xp_part = Breg;                   // 8 x 524,288
  float*  Bacc    = Breg;                   // (after reduce_xproj)
  __bf16* yh = (__bf16*)Dreg;
  __bf16* yl = (__bf16*)Dreg + 8388608;
  float*  op_part = xz;                     // 2 x 4,194,304 (xz dead by then)

  __bf16* wm16  = (__bf16*)wsm;
  __bf16* xpw_h = wm16;                     // 128*2048 (zero-padded rows 96..127)
  __bf16* xpw_l = wm16 + 262144;
  __bf16* dtw_h = wm16 + 524288;            // 2048*64
  __bf16* dtw_l = wm16 + 655360;
  __bf16* dth   = wm16 + 786432;            // 4096*64
  __bf16* dtl   = wm16 + 1048576;
  __bf16* ow_h  = wm16 + 1310720;           // 1024*2048
  __bf16* ow_l  = wm16 + 3407872;           // +2,097,152

  // ---- pre-convert inputs to bf16 hi/lo ----
  cvt_hilo_k<<<4096, 256, 0, stream>>>(hidden, hid_h, hid_l, 1048576);
  cvt_hilo_k<<<4096, 256, 0, stream>>>(in_proj_w, inw_h, inw_l, 1048576);
  cvt_hilo_k<<<192, 256, 0, stream>>>(x_proj_w, xpw_h, xpw_l, 49152);
  hipMemsetAsync(xpw_h + 196608, 0, 65536 * 2, stream);
  hipMemsetAsync(xpw_l + 196608, 0, 65536 * 2, stream);
  cvt_hilo_k<<<128, 256, 0, stream>>>(dt_proj_w, dtw_h, dtw_l, 32768);
  cvt_hilo_k<<<2048, 256, 0, stream>>>(out_proj_w, ow_h, ow_l, 524288);

  // xz = hidden @ in_proj_w^T   (M=4096, N=4096, K=1024)
  gemm3<<<dim3(32, 32, 1), 256, 0, stream>>>(hid_h, hid_l, inw_h, inw_l, xz,
                                             1024, 1024, 4096, 1024, 0);
  // x = silu(conv(x_pre) + b), + hi/lo
  conv_silu_k<<<dim3(8, 4096), 256, 0, stream>>>(xz, conv_w, conv_b, x, xh, xl);
  // x_dbl partials = x @ x_proj_w^T  (split-K S=8, kseg=256, padded N=128)
  gemm3<<<dim3(1, 32, 8), 256, 0, stream>>>(xh, xl, xpw_h, xpw_l, xp_part,
                                            2048, 2048, 128, 256, 0);
  reduce_xproj<<<2048, 256, 0, stream>>>(xp_part, x_dbl, dth, dtl);
  // delta = softplus(dt @ dt_proj_w^T)  (K=64)
  gemm3<<<dim3(16, 32, 1), 256, 0, stream>>>(dth, dtl, dtw_h, dtw_l, delta,
                                             64, 64, 2048, 64, 1);
  // chunked selective scan (writes y as bf16 hi/lo)
  scan_chunk1<<<dim3(32, NCHK, 4), 256, 0, stream>>>(delta, x, x_dbl, A_log, Bacc, sdsum);
  scan_chunk2<<<128, 256, 0, stream>>>(A_log, sdsum, Bacc);
  scan_chunk3<<<dim3(32, NCHK, 4), 256, 0, stream>>>(delta, x, xz, x_dbl, A_log, Dvec,
                                                     Bacc, yh, yl);
  // out partials = y @ out_proj_w^T (split-K S=2, kseg=1024)
  gemm3<<<dim3(8, 32, 2), 256, 0, stream>>>(yh, yl, ow_h, ow_l, op_part,
                                            2048, 2048, 1024, 1024, 0);
  reduce_oproj<<<4096, 256, 0, stream>>>(op_part, out);   // R4 fix: 4096 blocks
}

// Round 6
// 373.052 us; speedup vs baseline: 4.3629x; 1.0412x over previous
//
#include <hip/hip_runtime.h>
#include <math.h>

// ---------------------------------------------------------------------------
// Mamba block forward. b=4, l=1024, dm=1024, di=2048, n=16, r=64.
// GEMMs: pure-bf16 MFMA (hi/lo split, 3 MFMA/product), inputs pre-converted.
// R6: 2-phase double-buffered K-loop (counted vmcnt(8) + raw s_barrier),
//     all f32->bf16 conversions fused into ONE kernel.
// Scan: chunked 3-phase (32 chunks x 32 steps).
// ---------------------------------------------------------------------------

typedef __bf16 bf16x8 __attribute__((ext_vector_type(8)));
typedef __bf16 bf16x4 __attribute__((ext_vector_type(4)));
typedef float f32x4 __attribute__((ext_vector_type(4)));

__device__ __forceinline__ void gload16(const void* g, void* lds) {
  __builtin_amdgcn_global_load_lds((const __attribute__((address_space(1))) void*)g,
                                   (__attribute__((address_space(3))) void*)lds,
                                   16, 0, 0);
}

// ---------------- f32 -> bf16 hi/lo conversion ----------------
__device__ __forceinline__ void hilo4(float4 v, bf16x4& h, bf16x4& l) {
  h[0] = (__bf16)v.x; l[0] = (__bf16)(v.x - (float)h[0]);
  h[1] = (__bf16)v.y; l[1] = (__bf16)(v.y - (float)h[1]);
  h[2] = (__bf16)v.z; l[2] = (__bf16)(v.z - (float)h[2]);
  h[3] = (__bf16)v.w; l[3] = (__bf16)(v.w - (float)h[3]);
}

// One fused conversion pass over all five f32 tensors + xpw zero-pad.
// float4-unit segment boundaries (hardcoded for this problem's shapes).
__global__ __launch_bounds__(256) void cvt_all(
    const float* __restrict__ hidden, const float* __restrict__ in_proj_w,
    const float* __restrict__ x_proj_w, const float* __restrict__ dt_proj_w,
    const float* __restrict__ out_proj_w,
    __bf16* __restrict__ hid_h, __bf16* __restrict__ hid_l,
    __bf16* __restrict__ inw_h, __bf16* __restrict__ inw_l,
    __bf16* __restrict__ xpw_h, __bf16* __restrict__ xpw_l,
    __bf16* __restrict__ dtw_h, __bf16* __restrict__ dtw_l,
    __bf16* __restrict__ ow_h,  __bf16* __restrict__ ow_l)
{
  int i = blockIdx.x * 256 + threadIdx.x;
  const float* s; __bf16 *H, *L; int off;
  if (i < 1048576)      { s = hidden;     H = hid_h; L = hid_l; off = i; }
  else if (i < 2097152) { s = in_proj_w;  H = inw_h; L = inw_l; off = i - 1048576; }
  else if (i < 2146304) { s = x_proj_w;   H = xpw_h; L = xpw_l; off = i - 2097152; }
  else if (i < 2179072) { s = dt_proj_w;  H = dtw_h; L = dtw_l; off = i - 2146304; }
  else if (i < 2703360) { s = out_proj_w; H = ow_h;  L = ow_l;  off = i - 2179072; }
  else {  // zero-pad xpw rows 96..127: 16384 bf16x4 units each
    int j = i - 2703360;
    bf16x4 z = {};
    ((bf16x4*)(xpw_h + 196608))[j] = z;
    ((bf16x4*)(xpw_l + 196608))[j] = z;
    return;
  }
  float4 v = ((const float4*)s)[off];
  bf16x4 h, l;
  hilo4(v, h, l);
  ((bf16x4*)H)[off] = h;
  ((bf16x4*)L)[off] = l;
}

// ---------------------------------------------------------------------------
// NT GEMM, pure bf16 hi/lo: C = (Ah+Al)(Bh+Bl)^T ~ AhBh + AhBl + AlBh.
// Tile 128x128, TK=32, 4 waves (each stages one of the 4 LDS tiles).
// 2-phase double-buffer: stage tile t+1, vmcnt(8) for tile t's 8 older
// per-wave loads, raw s_barrier, compute, barrier, flip.
// grid (N/128, M/128, S): z splits K into kseg segments -> partial C slabs.
// ---------------------------------------------------------------------------
__global__ __launch_bounds__(256, 2) void gemm3(
    const __bf16* __restrict__ Ah, const __bf16* __restrict__ Al,
    const __bf16* __restrict__ Bh, const __bf16* __restrict__ Bl,
    float* __restrict__ C, int lda, int ldb, int ldc, int kseg, int epi)
{
  __shared__ __align__(16) __bf16 lds[2][4][128 * 32];

  const int tid = threadIdx.x;
  const int lane = tid & 63;
  const int laneL = lane & 15;
  const int laneH = lane >> 4;
  const int wave = tid >> 6;
  const int wm = wave >> 1;
  const int wn = wave & 1;
  const int row0 = blockIdx.y * 128;
  const int col0 = blockIdx.x * 128;
  const int k0base = blockIdx.z * kseg;

  // each wave stages one tile
  const __bf16* src = (wave == 0) ? Ah : (wave == 1) ? Al : (wave == 2) ? Bh : Bl;
  const int srcLd = (wave < 2) ? lda : ldb;
  const int srcRow0 = (wave < 2) ? row0 : col0;
  const int lr = lane >> 2;          // 0..15 row within 16-row group
  const int ls = lane & 3;           // 0..3 physical 16B slot
  const int ksl = (ls ^ ((lr >> 1) & 3)) * 8;  // pre-swizzled global k-offset
  const __bf16* gbase = src + (size_t)(srcRow0 + lr) * srcLd + ksl;

  const int rsw = (laneL >> 1) & 3;  // read-side swizzle
  f32x4 acc[4][4] = {};
  const int nk = kseg >> 5;

  // prologue: stage tile 0 into buffer 0
  {
    const __bf16* g = gbase + k0base;
    __bf16* dst = &lds[0][wave][lane * 8];
#pragma unroll
    for (int i = 0; i < 8; i++)
      gload16(g + (size_t)i * 16 * srcLd, dst + i * 512);
  }

  int cur = 0;
  for (int t = 0; t < nk; t++) {
    if (t + 1 < nk) {
      const __bf16* g = gbase + k0base + (t + 1) * 32;
      __bf16* dst = &lds[cur ^ 1][wave][lane * 8];
#pragma unroll
      for (int i = 0; i < 8; i++)
        gload16(g + (size_t)i * 16 * srcLd, dst + i * 512);
      asm volatile("s_waitcnt vmcnt(8)" ::: "memory");  // tile t's loads done
    } else {
      asm volatile("s_waitcnt vmcnt(0)" ::: "memory");
    }
    __builtin_amdgcn_s_barrier();
    __builtin_amdgcn_sched_barrier(0);

    const __bf16* sAh = lds[cur][0];
    const __bf16* sAl = lds[cur][1];
    const __bf16* sBh = lds[cur][2];
    const __bf16* sBl = lds[cur][3];

    bf16x8 ah[4], al[4], bh[4], bl[4];
#pragma unroll
    for (int i = 0; i < 4; i++) {
      int off = (wm * 64 + i * 16 + laneL) * 32 + ((laneH ^ rsw) << 3);
      ah[i] = *(const bf16x8*)&sAh[off];
      al[i] = *(const bf16x8*)&sAl[off];
    }
#pragma unroll
    for (int j = 0; j < 4; j++) {
      int off = (wn * 64 + j * 16 + laneL) * 32 + ((laneH ^ rsw) << 3);
      bh[j] = *(const bf16x8*)&sBh[off];
      bl[j] = *(const bf16x8*)&sBl[off];
    }
#pragma unroll
    for (int i = 0; i < 4; i++)
#pragma unroll
      for (int j = 0; j < 4; j++) {
        acc[i][j] = __builtin_amdgcn_mfma_f32_16x16x32_bf16(ah[i], bh[j], acc[i][j], 0, 0, 0);
        acc[i][j] = __builtin_amdgcn_mfma_f32_16x16x32_bf16(ah[i], bl[j], acc[i][j], 0, 0, 0);
        acc[i][j] = __builtin_amdgcn_mfma_f32_16x16x32_bf16(al[i], bh[j], acc[i][j], 0, 0, 0);
      }
    __builtin_amdgcn_sched_barrier(0);
    __builtin_amdgcn_s_barrier();   // all reads of lds[cur] done before re-stage
    cur ^= 1;
  }

  float* Cz = C + (size_t)blockIdx.z * gridDim.y * 128 * ldc;
#pragma unroll
  for (int i = 0; i < 4; i++) {
    int rr = row0 + wm * 64 + i * 16 + laneH * 4;
#pragma unroll
    for (int j = 0; j < 4; j++) {
      int cc = col0 + wn * 64 + j * 16 + laneL;
#pragma unroll
      for (int r = 0; r < 4; r++) {
        float v = acc[i][j][r];
        if (epi == 1) v = (v > 20.f) ? v : log1pf(expf(v));
        Cz[(size_t)(rr + r) * ldc + cc] = v;
      }
    }
  }
}

// ---------------- split-K reduces ----------------
__global__ __launch_bounds__(256) void reduce_xproj(
    const float* __restrict__ part, float* __restrict__ x_dbl,
    __bf16* __restrict__ dth, __bf16* __restrict__ dtl)
{
  int idx = blockIdx.x * 256 + threadIdx.x;   // 0 .. 4096*128-1
  int row = idx >> 7, col = idx & 127;
  float v = 0.f;
#pragma unroll
  for (int s = 0; s < 8; s++) v += part[(size_t)s * 524288 + idx];
  if (col < 96) x_dbl[(size_t)row * 96 + col] = v;
  if (col < 64) {
    __bf16 h = (__bf16)v;
    dth[(size_t)row * 64 + col] = h;
    dtl[(size_t)row * 64 + col] = (__bf16)(v - (float)h);
  }
}

__global__ __launch_bounds__(256) void reduce_oproj(
    const float* __restrict__ part, float* __restrict__ out)
{
  int i = blockIdx.x * 256 + threadIdx.x;     // 0 .. 4096*1024/4-1
  const float4 a = ((const float4*)part)[i];
  const float4 b = ((const float4*)part)[i + 1048576];
  float4 o = make_float4(a.x + b.x, a.y + b.y, a.z + b.z, a.w + b.w);
  ((float4*)out)[i] = o;
}

// ---------------- depthwise causal conv + bias + silu (+ hi/lo out) --------
__global__ __launch_bounds__(256) void conv_silu_k(
    const float* __restrict__ xz, const float* __restrict__ conv_w,
    const float* __restrict__ conv_b, float* __restrict__ x,
    __bf16* __restrict__ xh, __bf16* __restrict__ xl)
{
  const int d = blockIdx.x * 256 + threadIdx.x;
  const int row = blockIdx.y;
  const int l = row & 1023;
  const float4 w = ((const float4*)conv_w)[d];
  float acc = conv_b[d];
  const float* base = xz + (size_t)row * 4096 + d;
  if (l >= 3) acc = fmaf(base[-3 * 4096], w.x, acc);
  if (l >= 2) acc = fmaf(base[-2 * 4096], w.y, acc);
  if (l >= 1) acc = fmaf(base[-1 * 4096], w.z, acc);
  acc = fmaf(base[0], w.w, acc);
  float s = acc / (1.f + expf(-acc));
  size_t o = (size_t)row * 2048 + d;
  x[o] = s;
  __bf16 h = (__bf16)s;
  xh[o] = h;
  xl[o] = (__bf16)(s - (float)h);
}

// ---------------- chunked selective scan ----------------
#define NCHK 32
#define LC   32
#define DB   64
#define LOG2E 1.44269504f

__global__ __launch_bounds__(256) void scan_chunk1(
    const float* __restrict__ delta, const float* __restrict__ x,
    const float* __restrict__ x_dbl, const float* __restrict__ A_log,
    float* __restrict__ Bacc, float* __restrict__ sdsum)
{
  __shared__ __align__(16) float sdel[LC][DB];
  __shared__ __align__(16) float sx[LC][DB];
  __shared__ __align__(16) float sB[LC][16];

  const int tid = threadIdx.x;
  const int dl = tid >> 2;
  const int ng = tid & 3;
  const int d0 = blockIdx.x * DB;
  const int c = blockIdx.y, b = blockIdx.z;
  const int d = d0 + dl;
  const size_t row0 = (size_t)b * 1024 + c * LC;

  float a2[4];
#pragma unroll
  for (int i = 0; i < 4; i++) a2[i] = -expf(A_log[d * 16 + ng * 4 + i]) * LOG2E;

#pragma unroll
  for (int i = 0; i < 2; i++) {
    int f = tid + i * 256;
    int lr = f >> 4, c4 = (f & 15) * 4;
    size_t g = (row0 + lr) * 2048 + d0 + c4;
    *(float4*)&sdel[lr][c4] = *(const float4*)&delta[g];
    *(float4*)&sx[lr][c4]   = *(const float4*)&x[g];
  }
  if (tid < 128) {
    int lr = tid >> 2, n4 = (tid & 3) * 4;
    *(float4*)&sB[lr][n4] = *(const float4*)&x_dbl[(row0 + lr) * 96 + 64 + n4];
  }
  __syncthreads();

  float q0 = 0.f, q1 = 0.f, q2 = 0.f, q3 = 0.f, sd = 0.f;
#pragma unroll
  for (int t = 0; t < LC; t++) {
    float dlt = sdel[t][dl];
    float dx = dlt * sx[t][dl];
    const float4 Bv = *(const float4*)&sB[t][ng * 4];
    q0 = exp2f(dlt * a2[0]) * q0 + dx * Bv.x;
    q1 = exp2f(dlt * a2[1]) * q1 + dx * Bv.y;
    q2 = exp2f(dlt * a2[2]) * q2 + dx * Bv.z;
    q3 = exp2f(dlt * a2[3]) * q3 + dx * Bv.w;
    sd += dlt;
  }
  size_t o = ((size_t)(b * NCHK + c) * 2048 + d) * 16 + ng * 4;
  *(float4*)&Bacc[o] = make_float4(q0, q1, q2, q3);
  if (ng == 0) sdsum[(size_t)(b * NCHK + c) * 2048 + d] = sd;
}

__global__ __launch_bounds__(256) void scan_chunk2(
    const float* __restrict__ A_log, const float* __restrict__ sdsum,
    float* __restrict__ BaccH)
{
  const int g = blockIdx.x * 256 + threadIdx.x;
  const int ng = g & 3;
  const int d = (g >> 2) & 2047;
  const int b = g >> 13;
  float a2[4];
#pragma unroll
  for (int i = 0; i < 4; i++) a2[i] = -expf(A_log[d * 16 + ng * 4 + i]) * LOG2E;
  float h0 = 0.f, h1 = 0.f, h2 = 0.f, h3 = 0.f;
#pragma unroll 4
  for (int c = 0; c < NCHK; c++) {
    size_t o = ((size_t)(b * NCHK + c) * 2048 + d) * 16 + ng * 4;
    const float4 Q = *(const float4*)&BaccH[o];
    const float sd = sdsum[(size_t)(b * NCHK + c) * 2048 + d];
    *(float4*)&BaccH[o] = make_float4(h0, h1, h2, h3);
    h0 = exp2f(sd * a2[0]) * h0 + Q.x;
    h1 = exp2f(sd * a2[1]) * h1 + Q.y;
    h2 = exp2f(sd * a2[2]) * h2 + Q.z;
    h3 = exp2f(sd * a2[3]) * h3 + Q.w;
  }
}

__global__ __launch_bounds__(256) void scan_chunk3(
    const float* __restrict__ delta, const float* __restrict__ x,
    const float* __restrict__ xz, const float* __restrict__ x_dbl,
    const float* __restrict__ A_log, const float* __restrict__ Dvec,
    const float* __restrict__ Hstart,
    __bf16* __restrict__ yh, __bf16* __restrict__ yl)
{
  __shared__ __align__(16) float sdel[LC][DB];
  __shared__ __align__(16) float sx[LC][DB];
  __shared__ __align__(16) float szo[LC][DB];
  __shared__ __align__(16) float sB[LC][16];
  __shared__ __align__(16) float sC[LC][16];

  const int tid = threadIdx.x;
  const int dl = tid >> 2;
  const int ng = tid & 3;
  const int d0 = blockIdx.x * DB;
  const int c = blockIdx.y, b = blockIdx.z;
  const int d = d0 + dl;
  const size_t row0 = (size_t)b * 1024 + c * LC;

  float a2[4];
#pragma unroll
  for (int i = 0; i < 4; i++) a2[i] = -expf(A_log[d * 16 + ng * 4 + i]) * LOG2E;
  const float Dd = Dvec[d];

#pragma unroll
  for (int i = 0; i < 2; i++) {
    int f = tid + i * 256;
    int lr = f >> 4, c4 = (f & 15) * 4;
    size_t g = (row0 + lr) * 2048 + d0 + c4;
    *(float4*)&sdel[lr][c4] = *(const float4*)&delta[g];
    *(float4*)&sx[lr][c4]   = *(const float4*)&x[g];
    *(float4*)&szo[lr][c4]  = *(const float4*)&xz[(row0 + lr) * 4096 + 2048 + d0 + c4];
  }
  {
    int which = tid >> 7;
    int f = tid & 127;
    int lr = f >> 2, n4 = (f & 3) * 4;
    float4 v = *(const float4*)&x_dbl[(row0 + lr) * 96 + 64 + which * 16 + n4];
    if (which == 0) *(float4*)&sB[lr][n4] = v;
    else            *(float4*)&sC[lr][n4] = v;
  }
  __syncthreads();

  size_t ho = ((size_t)(b * NCHK + c) * 2048 + d) * 16 + ng * 4;
  const float4 hv = *(const float4*)&Hstart[ho];
  float h0 = hv.x, h1 = hv.y, h2 = hv.z, h3 = hv.w;

#pragma unroll
  for (int t = 0; t < LC; t++) {
    float dlt = sdel[t][dl];
    float xv = sx[t][dl];
    float dx = dlt * xv;
    const float4 Bv = *(const float4*)&sB[t][ng * 4];
    const float4 Cv = *(const float4*)&sC[t][ng * 4];
    float acc;
    h0 = exp2f(dlt * a2[0]) * h0 + dx * Bv.x; acc  = h0 * Cv.x;
    h1 = exp2f(dlt * a2[1]) * h1 + dx * Bv.y; acc += h1 * Cv.y;
    h2 = exp2f(dlt * a2[2]) * h2 + dx * Bv.z; acc += h2 * Cv.z;
    h3 = exp2f(dlt * a2[3]) * h3 + dx * Bv.w; acc += h3 * Cv.w;
    acc += __shfl_xor(acc, 1);
    acc += __shfl_xor(acc, 2);
    if (ng == 0) {
      float zv = szo[t][dl];
      szo[t][dl] = (acc + xv * Dd) * (zv / (1.f + expf(-zv)));
    }
  }
  __syncthreads();
#pragma unroll
  for (int i = 0; i < 2; i++) {
    int f = tid + i * 256;
    int lr = f >> 4, c4 = (f & 15) * 4;
    float4 v = *(const float4*)&szo[lr][c4];
    bf16x4 h, l;
    hilo4(v, h, l);
    size_t o = (row0 + lr) * 2048 + d0 + c4;
    *(bf16x4*)&yh[o] = h;
    *(bf16x4*)&yl[o] = l;
  }
}

extern "C" void kernel_launch(void* const* d_in, const int* in_sizes, int n_in,
                              void* d_out, int out_size, void* d_ws, size_t ws_size,
                              hipStream_t stream)
{
  const float* hidden     = (const float*)d_in[0];
  const float* in_proj_w  = (const float*)d_in[1];
  const float* conv_w     = (const float*)d_in[2];
  const float* conv_b     = (const float*)d_in[3];
  const float* x_proj_w   = (const float*)d_in[4];
  const float* dt_proj_w  = (const float*)d_in[5];
  const float* A_log      = (const float*)d_in[6];
  const float* Dvec       = (const float*)d_in[7];
  const float* out_proj_w = (const float*)d_in[8];
  float* out = (float*)d_out;

  // ---- workspace arena (f32 element offsets); aliased regions noted ----
  float* w = (float*)d_ws;
  float* xz    = w;                         // 16,777,216   [gemm1 .. scan3]; later op_part
  float* x     = xz + 16777216;             //  8,388,608   [conv .. scan3]
  float* x_dbl = x + 8388608;               //    393,216   [reduce_xp .. scan3]
  float* dreg  = x_dbl + 393216;            //  8,388,608   hid/inw cvt -> xh/xl -> delta
  float* Breg  = dreg + 8388608;            //  4,194,304   xp_part -> Bacc
  float* sdsum = Breg + 4194304;            //    262,144
  float* Dreg  = sdsum + 262144;            //  8,388,608   yh/yl
  float* wsm   = Dreg + 8388608;            //  2,752,512   small weights

  __bf16* d16   = (__bf16*)dreg;
  __bf16* hid_h = d16;                      // 4,194,304 bf16
  __bf16* hid_l = d16 + 4194304;
  __bf16* inw_h = d16 + 8388608;
  __bf16* inw_l = d16 + 12582912;
  __bf16* xh    = d16;                      // 8,388,608 bf16 (after gemm1)
  __bf16* xl    = d16 + 8388608;
  float*  delta = dreg;                     // f32 (after x_proj)
  float*  xp_part = Breg;                   // 8 x 524,288
  float*  Bacc    = Breg;                   // (after reduce_xproj)
  __bf16* yh = (__bf16*)Dreg;
  __bf16* yl = (__bf16*)Dreg + 8388608;
  float*  op_part = xz;                     // 2 x 4,194,304 (xz dead by then)

  __bf16* wm16  = (__bf16*)wsm;
  __bf16* xpw_h = wm16;                     // 128*2048 (rows 96..127 zero-padded)
  __bf16* xpw_l = wm16 + 262144;
  __bf16* dtw_h = wm16 + 524288;            // 2048*64
  __bf16* dtw_l = wm16 + 655360;
  __bf16* dth   = wm16 + 786432;            // 4096*64
  __bf16* dtl   = wm16 + 1048576;
  __bf16* ow_h  = wm16 + 1310720;           // 1024*2048
  __bf16* ow_l  = wm16 + 3407872;

  // ---- single fused conversion pass (replaces 5 cvt + 2 memset) ----
  cvt_all<<<10624, 256, 0, stream>>>(hidden, in_proj_w, x_proj_w, dt_proj_w,
                                     out_proj_w, hid_h, hid_l, inw_h, inw_l,
                                     xpw_h, xpw_l, dtw_h, dtw_l, ow_h, ow_l);

  // xz = hidden @ in_proj_w^T   (M=4096, N=4096, K=1024)
  gemm3<<<dim3(32, 32, 1), 256, 0, stream>>>(hid_h, hid_l, inw_h, inw_l, xz,
                                             1024, 1024, 4096, 1024, 0);
  // x = silu(conv(x_pre) + b), + hi/lo
  conv_silu_k<<<dim3(8, 4096), 256, 0, stream>>>(xz, conv_w, conv_b, x, xh, xl);
  // x_dbl partials = x @ x_proj_w^T  (split-K S=8, kseg=256, padded N=128)
  gemm3<<<dim3(1, 32, 8), 256, 0, stream>>>(xh, xl, xpw_h, xpw_l, xp_part,
                                            2048, 2048, 128, 256, 0);
  reduce_xproj<<<2048, 256, 0, stream>>>(xp_part, x_dbl, dth, dtl);
  // delta = softplus(dt @ dt_proj_w^T)  (K=64)
  gemm3<<<dim3(16, 32, 1), 256, 0, stream>>>(dth, dtl, dtw_h, dtw_l, delta,
                                             64, 64, 2048, 64, 1);
  // chunked selective scan (writes y as bf16 hi/lo)
  scan_chunk1<<<dim3(32, NCHK, 4), 256, 0, stream>>>(delta, x, x_dbl, A_log, Bacc, sdsum);
  scan_chunk2<<<128, 256, 0, stream>>>(A_log, sdsum, Bacc);
  scan_chunk3<<<dim3(32, NCHK, 4), 256, 0, stream>>>(delta, x, xz, x_dbl, A_log, Dvec,
                                                     Bacc, yh, yl);
  // out partials = y @ out_proj_w^T (split-K S=2, kseg=1024)
  gemm3<<<dim3(8, 32, 2), 256, 0, stream>>>(yh, yl, ow_h, ow_l, op_part,
                                            2048, 2048, 1024, 1024, 0);
  reduce_oproj<<<4096, 256, 0, stream>>>(op_part, out);
}

// Round 7
// 364.142 us; speedup vs baseline: 4.4697x; 1.0245x over previous
//
#include <hip/hip_runtime.h>
#include <math.h>

// ---------------------------------------------------------------------------
// Mamba block forward. b=4, l=1024, dm=1024, di=2048, n=16, r=64.
// GEMMs: pure-bf16 MFMA (hi/lo split, 3 MFMA/product), inputs pre-converted.
// R7: big GEMMs on 256x256 blocks, 8 waves x (128x64) wave-tile, dbuf LDS
//     (128 KB dynamic), counted vmcnt(8), setprio, XCD swizzle.
// Scan: chunked 3-phase (32 chunks x 32 steps).
// ---------------------------------------------------------------------------

typedef __bf16 bf16x8 __attribute__((ext_vector_type(8)));
typedef __bf16 bf16x4 __attribute__((ext_vector_type(4)));
typedef float f32x4 __attribute__((ext_vector_type(4)));

__device__ __forceinline__ void gload16(const void* g, void* lds_p) {
  __builtin_amdgcn_global_load_lds((const __attribute__((address_space(1))) void*)g,
                                   (__attribute__((address_space(3))) void*)lds_p,
                                   16, 0, 0);
}

// ---------------- f32 -> bf16 hi/lo conversion ----------------
__device__ __forceinline__ void hilo4(float4 v, bf16x4& h, bf16x4& l) {
  h[0] = (__bf16)v.x; l[0] = (__bf16)(v.x - (float)h[0]);
  h[1] = (__bf16)v.y; l[1] = (__bf16)(v.y - (float)h[1]);
  h[2] = (__bf16)v.z; l[2] = (__bf16)(v.z - (float)h[2]);
  h[3] = (__bf16)v.w; l[3] = (__bf16)(v.w - (float)h[3]);
}

// One fused conversion pass over all five f32 tensors + xpw zero-pad.
__global__ __launch_bounds__(256) void cvt_all(
    const float* __restrict__ hidden, const float* __restrict__ in_proj_w,
    const float* __restrict__ x_proj_w, const float* __restrict__ dt_proj_w,
    const float* __restrict__ out_proj_w,
    __bf16* __restrict__ hid_h, __bf16* __restrict__ hid_l,
    __bf16* __restrict__ inw_h, __bf16* __restrict__ inw_l,
    __bf16* __restrict__ xpw_h, __bf16* __restrict__ xpw_l,
    __bf16* __restrict__ dtw_h, __bf16* __restrict__ dtw_l,
    __bf16* __restrict__ ow_h,  __bf16* __restrict__ ow_l)
{
  int i = blockIdx.x * 256 + threadIdx.x;
  const float* s; __bf16 *H, *L; int off;
  if (i < 1048576)      { s = hidden;     H = hid_h; L = hid_l; off = i; }
  else if (i < 2097152) { s = in_proj_w;  H = inw_h; L = inw_l; off = i - 1048576; }
  else if (i < 2146304) { s = x_proj_w;   H = xpw_h; L = xpw_l; off = i - 2097152; }
  else if (i < 2179072) { s = dt_proj_w;  H = dtw_h; L = dtw_l; off = i - 2146304; }
  else if (i < 2703360) { s = out_proj_w; H = ow_h;  L = ow_l;  off = i - 2179072; }
  else {  // zero-pad xpw rows 96..127
    int j = i - 2703360;
    bf16x4 z = {};
    ((bf16x4*)(xpw_h + 196608))[j] = z;
    ((bf16x4*)(xpw_l + 196608))[j] = z;
    return;
  }
  float4 v = ((const float4*)s)[off];
  bf16x4 h, l;
  hilo4(v, h, l);
  ((bf16x4*)H)[off] = h;
  ((bf16x4*)L)[off] = l;
}

// ---------------------------------------------------------------------------
// Big NT GEMM: 256x256 block, 8 waves, wave tile 128x64 (acc 8x4 f32x4).
// C = AhBh + AhBl + AlBh, f32 accumulate. M,N % 256 == 0 (no guards).
// LDS: dynamic 128 KB = 2 bufs x 4 tiles(Ah,Al,Bh,Bl) x 256x32 bf16.
// grid (N/256, M/256, S): z = split-K segment of kseg (K % kseg == 0,
// kseg % 32 == 0); partial C slab s at C + s*gridDim.y*256*ldc.
// gridDim.x*gridDim.y must be a multiple of 8 (XCD swizzle).
// ---------------------------------------------------------------------------
__global__ __launch_bounds__(512, 2) void gemm256(
    const __bf16* __restrict__ Ah, const __bf16* __restrict__ Al,
    const __bf16* __restrict__ Bh, const __bf16* __restrict__ Bl,
    float* __restrict__ C, int lda, int ldb, int ldc, int kseg)
{
  extern __shared__ __align__(16) __bf16 lds[];   // 2 x 32768 elements

  const int tid = threadIdx.x;
  const int lane = tid & 63;
  const int laneL = lane & 15;
  const int laneH = lane >> 4;
  const int wave = tid >> 6;        // 0..7
  const int wm = wave >> 2;         // 0..1 (M half)
  const int wn = wave & 3;          // 0..3 (N quarter)

  // bijective XCD swizzle over the (x,y) grid plane
  const int nbx = gridDim.x;
  const int nwg = nbx * gridDim.y;
  int wg = blockIdx.y * nbx + blockIdx.x;
  wg = (wg & 7) * (nwg >> 3) + (wg >> 3);
  const int row0 = (wg / nbx) * 256;
  const int col0 = (wg % nbx) * 256;
  const int k0base = blockIdx.z * kseg;

  // staging role: wave -> (matrix, row-half)
  const int mat = wave >> 1;        // 0 Ah, 1 Al, 2 Bh, 3 Bl
  const int half = wave & 1;
  const __bf16* src = (mat == 0) ? Ah : (mat == 1) ? Al : (mat == 2) ? Bh : Bl;
  const int srcLd = (mat < 2) ? lda : ldb;
  const int srcRow0 = ((mat < 2) ? row0 : col0) + half * 128;
  const int lr = lane >> 2;          // 0..15
  const int ls = lane & 3;           // 0..3
  const int ksl = (ls ^ ((lr >> 1) & 3)) * 8;   // pre-swizzled k offset
  const __bf16* gbase = src + (size_t)(srcRow0 + lr) * srcLd + ksl;
  const int dstoff = mat * 8192 + half * 4096 + lane * 8;

  const int rsw = (laneL >> 1) & 3;  // read-side swizzle
  f32x4 acc[8][4] = {};
  const int nk = kseg >> 5;

  // prologue: stage tile 0 into buffer 0
  {
    const __bf16* g = gbase + k0base;
    __bf16* dst = lds + dstoff;
#pragma unroll
    for (int i = 0; i < 8; i++)
      gload16(g + (size_t)i * 16 * srcLd, dst + i * 512);
  }

  int cur = 0;
  for (int t = 0; t < nk; t++) {
    if (t + 1 < nk) {
      const __bf16* g = gbase + k0base + (t + 1) * 32;
      __bf16* dst = lds + (cur ^ 1) * 32768 + dstoff;
#pragma unroll
      for (int i = 0; i < 8; i++)
        gload16(g + (size_t)i * 16 * srcLd, dst + i * 512);
      asm volatile("s_waitcnt vmcnt(8)" ::: "memory");  // tile t complete
    } else {
      asm volatile("s_waitcnt vmcnt(0)" ::: "memory");
    }
    __builtin_amdgcn_s_barrier();
    __builtin_amdgcn_sched_barrier(0);

    const __bf16* base = lds + cur * 32768;
    const __bf16* sAh = base;
    const __bf16* sAl = base + 8192;
    const __bf16* sBh = base + 16384;
    const __bf16* sBl = base + 24576;

    bf16x8 bh[4], bl[4];
#pragma unroll
    for (int j = 0; j < 4; j++) {
      int off = (wn * 64 + j * 16 + laneL) * 32 + ((laneH ^ rsw) << 3);
      bh[j] = *(const bf16x8*)&sBh[off];
      bl[j] = *(const bf16x8*)&sBl[off];
    }
    __builtin_amdgcn_s_setprio(1);
#pragma unroll
    for (int i = 0; i < 8; i++) {
      int off = (wm * 128 + i * 16 + laneL) * 32 + ((laneH ^ rsw) << 3);
      bf16x8 ah = *(const bf16x8*)&sAh[off];
      bf16x8 al = *(const bf16x8*)&sAl[off];
#pragma unroll
      for (int j = 0; j < 4; j++) {
        acc[i][j] = __builtin_amdgcn_mfma_f32_16x16x32_bf16(ah, bh[j], acc[i][j], 0, 0, 0);
        acc[i][j] = __builtin_amdgcn_mfma_f32_16x16x32_bf16(ah, bl[j], acc[i][j], 0, 0, 0);
        acc[i][j] = __builtin_amdgcn_mfma_f32_16x16x32_bf16(al, bh[j], acc[i][j], 0, 0, 0);
      }
    }
    __builtin_amdgcn_s_setprio(0);
    __builtin_amdgcn_sched_barrier(0);
    __builtin_amdgcn_s_barrier();   // all reads done before re-stage
    cur ^= 1;
  }

  float* Cz = C + (size_t)blockIdx.z * gridDim.y * 256 * ldc;
#pragma unroll
  for (int i = 0; i < 8; i++) {
    int rr = row0 + wm * 128 + i * 16 + laneH * 4;
#pragma unroll
    for (int j = 0; j < 4; j++) {
      int cc = col0 + wn * 64 + j * 16 + laneL;
#pragma unroll
      for (int r = 0; r < 4; r++)
        Cz[(size_t)(rr + r) * ldc + cc] = acc[i][j][r];
    }
  }
}

// ---------------------------------------------------------------------------
// Small NT GEMM (128x128, 4 waves) for x_proj / dt_proj. Unchanged from R6.
// ---------------------------------------------------------------------------
__global__ __launch_bounds__(256, 2) void gemm3(
    const __bf16* __restrict__ Ah, const __bf16* __restrict__ Al,
    const __bf16* __restrict__ Bh, const __bf16* __restrict__ Bl,
    float* __restrict__ C, int lda, int ldb, int ldc, int kseg, int epi)
{
  __shared__ __align__(16) __bf16 lds[2][4][128 * 32];

  const int tid = threadIdx.x;
  const int lane = tid & 63;
  const int laneL = lane & 15;
  const int laneH = lane >> 4;
  const int wave = tid >> 6;
  const int wm = wave >> 1;
  const int wn = wave & 1;
  const int row0 = blockIdx.y * 128;
  const int col0 = blockIdx.x * 128;
  const int k0base = blockIdx.z * kseg;

  const __bf16* src = (wave == 0) ? Ah : (wave == 1) ? Al : (wave == 2) ? Bh : Bl;
  const int srcLd = (wave < 2) ? lda : ldb;
  const int srcRow0 = (wave < 2) ? row0 : col0;
  const int lr = lane >> 2;
  const int ls = lane & 3;
  const int ksl = (ls ^ ((lr >> 1) & 3)) * 8;
  const __bf16* gbase = src + (size_t)(srcRow0 + lr) * srcLd + ksl;

  const int rsw = (laneL >> 1) & 3;
  f32x4 acc[4][4] = {};
  const int nk = kseg >> 5;

  {
    const __bf16* g = gbase + k0base;
    __bf16* dst = &lds[0][wave][lane * 8];
#pragma unroll
    for (int i = 0; i < 8; i++)
      gload16(g + (size_t)i * 16 * srcLd, dst + i * 512);
  }

  int cur = 0;
  for (int t = 0; t < nk; t++) {
    if (t + 1 < nk) {
      const __bf16* g = gbase + k0base + (t + 1) * 32;
      __bf16* dst = &lds[cur ^ 1][wave][lane * 8];
#pragma unroll
      for (int i = 0; i < 8; i++)
        gload16(g + (size_t)i * 16 * srcLd, dst + i * 512);
      asm volatile("s_waitcnt vmcnt(8)" ::: "memory");
    } else {
      asm volatile("s_waitcnt vmcnt(0)" ::: "memory");
    }
    __builtin_amdgcn_s_barrier();
    __builtin_amdgcn_sched_barrier(0);

    const __bf16* sAh = lds[cur][0];
    const __bf16* sAl = lds[cur][1];
    const __bf16* sBh = lds[cur][2];
    const __bf16* sBl = lds[cur][3];

    bf16x8 ah[4], al[4], bh[4], bl[4];
#pragma unroll
    for (int i = 0; i < 4; i++) {
      int off = (wm * 64 + i * 16 + laneL) * 32 + ((laneH ^ rsw) << 3);
      ah[i] = *(const bf16x8*)&sAh[off];
      al[i] = *(const bf16x8*)&sAl[off];
    }
#pragma unroll
    for (int j = 0; j < 4; j++) {
      int off = (wn * 64 + j * 16 + laneL) * 32 + ((laneH ^ rsw) << 3);
      bh[j] = *(const bf16x8*)&sBh[off];
      bl[j] = *(const bf16x8*)&sBl[off];
    }
#pragma unroll
    for (int i = 0; i < 4; i++)
#pragma unroll
      for (int j = 0; j < 4; j++) {
        acc[i][j] = __builtin_amdgcn_mfma_f32_16x16x32_bf16(ah[i], bh[j], acc[i][j], 0, 0, 0);
        acc[i][j] = __builtin_amdgcn_mfma_f32_16x16x32_bf16(ah[i], bl[j], acc[i][j], 0, 0, 0);
        acc[i][j] = __builtin_amdgcn_mfma_f32_16x16x32_bf16(al[i], bh[j], acc[i][j], 0, 0, 0);
      }
    __builtin_amdgcn_sched_barrier(0);
    __builtin_amdgcn_s_barrier();
    cur ^= 1;
  }

  float* Cz = C + (size_t)blockIdx.z * gridDim.y * 128 * ldc;
#pragma unroll
  for (int i = 0; i < 4; i++) {
    int rr = row0 + wm * 64 + i * 16 + laneH * 4;
#pragma unroll
    for (int j = 0; j < 4; j++) {
      int cc = col0 + wn * 64 + j * 16 + laneL;
#pragma unroll
      for (int r = 0; r < 4; r++) {
        float v = acc[i][j][r];
        if (epi == 1) v = (v > 20.f) ? v : log1pf(expf(v));
        Cz[(size_t)(rr + r) * ldc + cc] = v;
      }
    }
  }
}

// ---------------- split-K reduces ----------------
__global__ __launch_bounds__(256) void reduce_xproj(
    const float* __restrict__ part, float* __restrict__ x_dbl,
    __bf16* __restrict__ dth, __bf16* __restrict__ dtl)
{
  int idx = blockIdx.x * 256 + threadIdx.x;   // 0 .. 4096*128-1
  int row = idx >> 7, col = idx & 127;
  float v = 0.f;
#pragma unroll
  for (int s = 0; s < 8; s++) v += part[(size_t)s * 524288 + idx];
  if (col < 96) x_dbl[(size_t)row * 96 + col] = v;
  if (col < 64) {
    __bf16 h = (__bf16)v;
    dth[(size_t)row * 64 + col] = h;
    dtl[(size_t)row * 64 + col] = (__bf16)(v - (float)h);
  }
}

// out_proj: 4 partials (4096 x 1024), sum -> out.
__global__ __launch_bounds__(256) void reduce_oproj(
    const float* __restrict__ part, float* __restrict__ out)
{
  int i = blockIdx.x * 256 + threadIdx.x;     // 0 .. 1048575 float4 units
  const float4 a = ((const float4*)part)[i];
  const float4 b = ((const float4*)part)[i + 1048576];
  const float4 c = ((const float4*)part)[i + 2097152];
  const float4 d = ((const float4*)part)[i + 3145728];
  float4 o = make_float4(a.x + b.x + c.x + d.x, a.y + b.y + c.y + d.y,
                         a.z + b.z + c.z + d.z, a.w + b.w + c.w + d.w);
  ((float4*)out)[i] = o;
}

// ---------------- depthwise causal conv + bias + silu (+ hi/lo out) --------
__global__ __launch_bounds__(256) void conv_silu_k(
    const float* __restrict__ xz, const float* __restrict__ conv_w,
    const float* __restrict__ conv_b, float* __restrict__ x,
    __bf16* __restrict__ xh, __bf16* __restrict__ xl)
{
  const int d = blockIdx.x * 256 + threadIdx.x;
  const int row = blockIdx.y;
  const int l = row & 1023;
  const float4 w = ((const float4*)conv_w)[d];
  float acc = conv_b[d];
  const float* base = xz + (size_t)row * 4096 + d;
  if (l >= 3) acc = fmaf(base[-3 * 4096], w.x, acc);
  if (l >= 2) acc = fmaf(base[-2 * 4096], w.y, acc);
  if (l >= 1) acc = fmaf(base[-1 * 4096], w.z, acc);
  acc = fmaf(base[0], w.w, acc);
  float s = acc / (1.f + expf(-acc));
  size_t o = (size_t)row * 2048 + d;
  x[o] = s;
  __bf16 h = (__bf16)s;
  xh[o] = h;
  xl[o] = (__bf16)(s - (float)h);
}

// ---------------- chunked selective scan ----------------
#define NCHK 32
#define LC   32
#define DB   64
#define LOG2E 1.44269504f

__global__ __launch_bounds__(256) void scan_chunk1(
    const float* __restrict__ delta, const float* __restrict__ x,
    const float* __restrict__ x_dbl, const float* __restrict__ A_log,
    float* __restrict__ Bacc, float* __restrict__ sdsum)
{
  __shared__ __align__(16) float sdel[LC][DB];
  __shared__ __align__(16) float sx[LC][DB];
  __shared__ __align__(16) float sB[LC][16];

  const int tid = threadIdx.x;
  const int dl = tid >> 2;
  const int ng = tid & 3;
  const int d0 = blockIdx.x * DB;
  const int c = blockIdx.y, b = blockIdx.z;
  const int d = d0 + dl;
  const size_t row0 = (size_t)b * 1024 + c * LC;

  float a2[4];
#pragma unroll
  for (int i = 0; i < 4; i++) a2[i] = -expf(A_log[d * 16 + ng * 4 + i]) * LOG2E;

#pragma unroll
  for (int i = 0; i < 2; i++) {
    int f = tid + i * 256;
    int lr = f >> 4, c4 = (f & 15) * 4;
    size_t g = (row0 + lr) * 2048 + d0 + c4;
    *(float4*)&sdel[lr][c4] = *(const float4*)&delta[g];
    *(float4*)&sx[lr][c4]   = *(const float4*)&x[g];
  }
  if (tid < 128) {
    int lr = tid >> 2, n4 = (tid & 3) * 4;
    *(float4*)&sB[lr][n4] = *(const float4*)&x_dbl[(row0 + lr) * 96 + 64 + n4];
  }
  __syncthreads();

  float q0 = 0.f, q1 = 0.f, q2 = 0.f, q3 = 0.f, sd = 0.f;
#pragma unroll
  for (int t = 0; t < LC; t++) {
    float dlt = sdel[t][dl];
    float dx = dlt * sx[t][dl];
    const float4 Bv = *(const float4*)&sB[t][ng * 4];
    q0 = exp2f(dlt * a2[0]) * q0 + dx * Bv.x;
    q1 = exp2f(dlt * a2[1]) * q1 + dx * Bv.y;
    q2 = exp2f(dlt * a2[2]) * q2 + dx * Bv.z;
    q3 = exp2f(dlt * a2[3]) * q3 + dx * Bv.w;
    sd += dlt;
  }
  size_t o = ((size_t)(b * NCHK + c) * 2048 + d) * 16 + ng * 4;
  *(float4*)&Bacc[o] = make_float4(q0, q1, q2, q3);
  if (ng == 0) sdsum[(size_t)(b * NCHK + c) * 2048 + d] = sd;
}

__global__ __launch_bounds__(256) void scan_chunk2(
    const float* __restrict__ A_log, const float* __restrict__ sdsum,
    float* __restrict__ BaccH)
{
  const int g = blockIdx.x * 256 + threadIdx.x;
  const int ng = g & 3;
  const int d = (g >> 2) & 2047;
  const int b = g >> 13;
  float a2[4];
#pragma unroll
  for (int i = 0; i < 4; i++) a2[i] = -expf(A_log[d * 16 + ng * 4 + i]) * LOG2E;
  float h0 = 0.f, h1 = 0.f, h2 = 0.f, h3 = 0.f;
#pragma unroll 4
  for (int c = 0; c < NCHK; c++) {
    size_t o = ((size_t)(b * NCHK + c) * 2048 + d) * 16 + ng * 4;
    const float4 Q = *(const float4*)&BaccH[o];
    const float sd = sdsum[(size_t)(b * NCHK + c) * 2048 + d];
    *(float4*)&BaccH[o] = make_float4(h0, h1, h2, h3);
    h0 = exp2f(sd * a2[0]) * h0 + Q.x;
    h1 = exp2f(sd * a2[1]) * h1 + Q.y;
    h2 = exp2f(sd * a2[2]) * h2 + Q.z;
    h3 = exp2f(sd * a2[3]) * h3 + Q.w;
  }
}

__global__ __launch_bounds__(256) void scan_chunk3(
    const float* __restrict__ delta, const float* __restrict__ x,
    const float* __restrict__ xz, const float* __restrict__ x_dbl,
    const float* __restrict__ A_log, const float* __restrict__ Dvec,
    const float* __restrict__ Hstart,
    __bf16* __restrict__ yh, __bf16* __restrict__ yl)
{
  __shared__ __align__(16) float sdel[LC][DB];
  __shared__ __align__(16) float sx[LC][DB];
  __shared__ __align__(16) float szo[LC][DB];
  __shared__ __align__(16) float sB[LC][16];
  __shared__ __align__(16) float sC[LC][16];

  const int tid = threadIdx.x;
  const int dl = tid >> 2;
  const int ng = tid & 3;
  const int d0 = blockIdx.x * DB;
  const int c = blockIdx.y, b = blockIdx.z;
  const int d = d0 + dl;
  const size_t row0 = (size_t)b * 1024 + c * LC;

  float a2[4];
#pragma unroll
  for (int i = 0; i < 4; i++) a2[i] = -expf(A_log[d * 16 + ng * 4 + i]) * LOG2E;
  const float Dd = Dvec[d];

#pragma unroll
  for (int i = 0; i < 2; i++) {
    int f = tid + i * 256;
    int lr = f >> 4, c4 = (f & 15) * 4;
    size_t g = (row0 + lr) * 2048 + d0 + c4;
    *(float4*)&sdel[lr][c4] = *(const float4*)&delta[g];
    *(float4*)&sx[lr][c4]   = *(const float4*)&x[g];
    *(float4*)&szo[lr][c4]  = *(const float4*)&xz[(row0 + lr) * 4096 + 2048 + d0 + c4];
  }
  {
    int which = tid >> 7;
    int f = tid & 127;
    int lr = f >> 2, n4 = (f & 3) * 4;
    float4 v = *(const float4*)&x_dbl[(row0 + lr) * 96 + 64 + which * 16 + n4];
    if (which == 0) *(float4*)&sB[lr][n4] = v;
    else            *(float4*)&sC[lr][n4] = v;
  }
  __syncthreads();

  size_t ho = ((size_t)(b * NCHK + c) * 2048 + d) * 16 + ng * 4;
  const float4 hv = *(const float4*)&Hstart[ho];
  float h0 = hv.x, h1 = hv.y, h2 = hv.z, h3 = hv.w;

#pragma unroll
  for (int t = 0; t < LC; t++) {
    float dlt = sdel[t][dl];
    float xv = sx[t][dl];
    float dx = dlt * xv;
    const float4 Bv = *(const float4*)&sB[t][ng * 4];
    const float4 Cv = *(const float4*)&sC[t][ng * 4];
    float acc;
    h0 = exp2f(dlt * a2[0]) * h0 + dx * Bv.x; acc  = h0 * Cv.x;
    h1 = exp2f(dlt * a2[1]) * h1 + dx * Bv.y; acc += h1 * Cv.y;
    h2 = exp2f(dlt * a2[2]) * h2 + dx * Bv.z; acc += h2 * Cv.z;
    h3 = exp2f(dlt * a2[3]) * h3 + dx * Bv.w; acc += h3 * Cv.w;
    acc += __shfl_xor(acc, 1);
    acc += __shfl_xor(acc, 2);
    if (ng == 0) {
      float zv = szo[t][dl];
      szo[t][dl] = (acc + xv * Dd) * (zv / (1.f + expf(-zv)));
    }
  }
  __syncthreads();
#pragma unroll
  for (int i = 0; i < 2; i++) {
    int f = tid + i * 256;
    int lr = f >> 4, c4 = (f & 15) * 4;
    float4 v = *(const float4*)&szo[lr][c4];
    bf16x4 h, l;
    hilo4(v, h, l);
    size_t o = (row0 + lr) * 2048 + d0 + c4;
    *(bf16x4*)&yh[o] = h;
    *(bf16x4*)&yl[o] = l;
  }
}

extern "C" void kernel_launch(void* const* d_in, const int* in_sizes, int n_in,
                              void* d_out, int out_size, void* d_ws, size_t ws_size,
                              hipStream_t stream)
{
  const float* hidden     = (const float*)d_in[0];
  const float* in_proj_w  = (const float*)d_in[1];
  const float* conv_w     = (const float*)d_in[2];
  const float* conv_b     = (const float*)d_in[3];
  const float* x_proj_w   = (const float*)d_in[4];
  const float* dt_proj_w  = (const float*)d_in[5];
  const float* A_log      = (const float*)d_in[6];
  const float* Dvec       = (const float*)d_in[7];
  const float* out_proj_w = (const float*)d_in[8];
  float* out = (float*)d_out;

  // ---- workspace arena (f32 element offsets); aliased regions noted ----
  float* w = (float*)d_ws;
  float* xz    = w;                         // 16,777,216   [gemm1 .. scan3]; later op_part (4 slabs)
  float* x     = xz + 16777216;             //  8,388,608   [conv .. scan3]
  float* x_dbl = x + 8388608;               //    393,216   [reduce_xp .. scan3]
  float* dreg  = x_dbl + 393216;            //  8,388,608   hid/inw cvt -> xh/xl -> delta
  float* Breg  = dreg + 8388608;            //  4,194,304   xp_part -> Bacc
  float* sdsum = Breg + 4194304;            //    262,144
  float* Dreg  = sdsum + 262144;            //  8,388,608   yh/yl
  float* wsm   = Dreg + 8388608;            //  2,752,512   small weights

  __bf16* d16   = (__bf16*)dreg;
  __bf16* hid_h = d16;                      // 4,194,304 bf16
  __bf16* hid_l = d16 + 4194304;
  __bf16* inw_h = d16 + 8388608;
  __bf16* inw_l = d16 + 12582912;
  __bf16* xh    = d16;                      // 8,388,608 bf16 (after gemm1)
  __bf16* xl    = d16 + 8388608;
  float*  delta = dreg;                     // f32 (after x_proj)
  float*  xp_part = Breg;                   // 8 x 524,288
  float*  Bacc    = Breg;                   // (after reduce_xproj)
  __bf16* yh = (__bf16*)Dreg;
  __bf16* yl = (__bf16*)Dreg + 8388608;
  float*  op_part = xz;                     // 4 x 4,194,304 (xz dead by then)

  __bf16* wm16  = (__bf16*)wsm;
  __bf16* xpw_h = wm16;                     // 128*2048 (rows 96..127 zero-padded)
  __bf16* xpw_l = wm16 + 262144;
  __bf16* dtw_h = wm16 + 524288;            // 2048*64
  __bf16* dtw_l = wm16 + 655360;
  __bf16* dth   = wm16 + 786432;            // 4096*64
  __bf16* dtl   = wm16 + 1048576;
  __bf16* ow_h  = wm16 + 1310720;           // 1024*2048
  __bf16* ow_l  = wm16 + 3407872;

  // ---- single fused conversion pass ----
  cvt_all<<<10624, 256, 0, stream>>>(hidden, in_proj_w, x_proj_w, dt_proj_w,
                                     out_proj_w, hid_h, hid_l, inw_h, inw_l,
                                     xpw_h, xpw_l, dtw_h, dtw_l, ow_h, ow_l);

  // xz = hidden @ in_proj_w^T   (M=4096, N=4096, K=1024) — 256x256 blocks
  gemm256<<<dim3(16, 16, 1), 512, 131072, stream>>>(hid_h, hid_l, inw_h, inw_l,
                                                    xz, 1024, 1024, 4096, 1024);
  // x = silu(conv(x_pre) + b), + hi/lo
  conv_silu_k<<<dim3(8, 4096), 256, 0, stream>>>(xz, conv_w, conv_b, x, xh, xl);
  // x_dbl partials = x @ x_proj_w^T  (split-K S=8, kseg=256, padded N=128)
  gemm3<<<dim3(1, 32, 8), 256, 0, stream>>>(xh, xl, xpw_h, xpw_l, xp_part,
                                            2048, 2048, 128, 256, 0);
  reduce_xproj<<<2048, 256, 0, stream>>>(xp_part, x_dbl, dth, dtl);
  // delta = softplus(dt @ dt_proj_w^T)  (K=64)
  gemm3<<<dim3(16, 32, 1), 256, 0, stream>>>(dth, dtl, dtw_h, dtw_l, delta,
                                             64, 64, 2048, 64, 1);
  // chunked selective scan (writes y as bf16 hi/lo)
  scan_chunk1<<<dim3(32, NCHK, 4), 256, 0, stream>>>(delta, x, x_dbl, A_log, Bacc, sdsum);
  scan_chunk2<<<128, 256, 0, stream>>>(A_log, sdsum, Bacc);
  scan_chunk3<<<dim3(32, NCHK, 4), 256, 0, stream>>>(delta, x, xz, x_dbl, A_log, Dvec,
                                                     Bacc, yh, yl);
  // out partials = y @ out_proj_w^T (256x256 blocks, split-K S=4, kseg=512)
  gemm256<<<dim3(4, 16, 4), 512, 131072, stream>>>(yh, yl, ow_h, ow_l, op_part,
                                                   2048, 2048, 1024, 512);
  reduce_oproj<<<4096, 256, 0, stream>>>(op_part, out);
}